// Round 10
// baseline (434.165 us; speedup 1.0000x reference)
//
#include <hip/hip_runtime.h>
#include <hip/hip_bf16.h>

// Channel attention (4 heads, dilated 3x3 key convs d=1,2,4,8), f16 MFMA pipeline.
// R10: convk split-buffer pipeline -- halo double-buffered (staged 2 chunks ahead,
// counted vmcnt(7), never drained mid-loop), weights single-buffered (L2-hot,
// short wait). 77.8KB LDS keeps 2 blocks/CU.
//
// ws layout (bytes):
//   kbuf : [0,           67108864)   k  f16 [h][b][p][n]
//   vT   : [67108864,   134217728)   v  f16 [h][b][n][p]   (pixel-major)
//   attn : [134217728,  134479872)   attn f16 [h][b][o][p]
//   Wqv  : [134479872,  134742016)   f16 (512x256)
//   Wkb  : [134742016,  135921664)   f16 [h][t][ks32][p64][8]  (MFMA A-frag native)
//   zpage: [135921664,  135922176)   zeros (OOB load source, 512 B)
// d_out reused as scratch (dead before final kernel):
//   xT   : bytes [0, 64Mi)   f16 [b][n][c]
//   q    : bytes [64Mi,128Mi) f16 [h][b][o][n]
//   part : bytes [0, 4Mi)    fp32 partial scores (written AFTER conv, xT dead)

typedef __attribute__((ext_vector_type(8))) _Float16 f16x8;
typedef __attribute__((ext_vector_type(4))) float f32x4;
typedef __attribute__((ext_vector_type(16))) float f32x16;

__device__ __forceinline__ unsigned short f2h(float f) {
  union { _Float16 h; unsigned short u; } v;
  v.h = (_Float16)f;
  return v.u;
}

__device__ __forceinline__ f32x4 mfma16(f16x8 a, f16x8 b, f32x4 c) {
  return __builtin_amdgcn_mfma_f32_16x16x32_f16(a, b, c, 0, 0, 0);
}
__device__ __forceinline__ f32x16 mfma32(f16x8 a, f16x8 b, f32x16 c) {
  return __builtin_amdgcn_mfma_f32_32x32x16_f16(a, b, c, 0, 0, 0);
}

// swizzled index into a [R][64]-ushort tile (128B rows): XOR bits 4..6 of byte off
__device__ __forceinline__ int sw(int row, int c) {
  return row * 64 + ((((c << 1) ^ ((row & 7) << 4)) >> 1));
}

// ---------------- weight prep ----------------
__global__ __launch_bounds__(256) void prep(const float* __restrict__ Wq,
                                            const float* __restrict__ Wv,
                                            const float* __restrict__ Wk,
                                            unsigned short* __restrict__ Wqv,
                                            unsigned short* __restrict__ Wkb,
                                            unsigned short* __restrict__ zp) {
  int i = blockIdx.x * 256 + threadIdx.x;
  if (blockIdx.x == 0) zp[threadIdx.x] = 0;  // 512 B zero page
  const int total = 131072 + 589824;
  if (i >= total) return;
  if (i < 131072) {
    Wqv[i] = f2h(i < 65536 ? Wq[i] : Wv[i - 65536]);
  } else {
    int j = i - 131072;  // (((h*9+t)*32 + ks)*64 + p)*8 + jj
    int jj = j & 7;
    int p = (j >> 3) & 63;
    int ks = (j >> 9) & 31;
    int ht = j >> 14;
    int t = ht % 9;
    int h = ht / 9;
    Wkb[j] = f2h(Wk[(size_t)((h * 64 + p) * 256 + ks * 8 + jj) * 9 + t]);
  }
}

// ---------------- x (b,c,n) fp32 -> xT (b,n,c) f16 ----------------
__global__ __launch_bounds__(256) void xpose(const float* __restrict__ x,
                                             unsigned short* __restrict__ xT) {
  __shared__ unsigned short tile[64][66];
  int n0 = blockIdx.x * 64, c0 = blockIdx.y * 64, b = blockIdx.z;
  int t = threadIdx.x;
  int r = t >> 2, q = t & 3;
  const float* src = x + (size_t)b * 4194304 + (size_t)(c0 + r) * 16384 + n0 + q * 16;
#pragma unroll
  for (int i = 0; i < 4; i++) {
    float4 v = *(const float4*)(src + i * 4);
    tile[r][q * 16 + i * 4 + 0] = f2h(v.x);
    tile[r][q * 16 + i * 4 + 1] = f2h(v.y);
    tile[r][q * 16 + i * 4 + 2] = f2h(v.z);
    tile[r][q * 16 + i * 4 + 3] = f2h(v.w);
  }
  __syncthreads();
  int c = t & 63, pq = t >> 6;
  unsigned short* dst = xT + (size_t)b * 4194304 + (size_t)n0 * 256 + c0 + c;
#pragma unroll
  for (int i = 0; i < 16; i++) {
    int px = i * 4 + pq;
    dst[(size_t)px * 256] = tile[c][px];
  }
}

// ---------------- Q/V projection: q-tile + v-tile paired, shared x staging -----
__global__ __launch_bounds__(256) void proj(const unsigned short* __restrict__ xT,
                                            const unsigned short* __restrict__ Wqv,
                                            const float* __restrict__ bq,
                                            const float* __restrict__ bv,
                                            unsigned short* __restrict__ qout,
                                            unsigned short* __restrict__ vT) {
  __shared__ __align__(16) unsigned short As[2][64 * 64];
  __shared__ __align__(16) unsigned short Bs[256 * 64];
  int n0 = blockIdx.x * 256, y = blockIdx.y, b = blockIdx.z;
  int h = y;  // head
  int tid = threadIdx.x, lane = tid & 63, w = tid >> 6;
  int l15 = lane & 15, uq = lane >> 4;
  const f32x4 fz = {0.f, 0.f, 0.f, 0.f};
  f32x4 acc[2][4][4];
#pragma unroll
  for (int m = 0; m < 2; m++)
#pragma unroll
    for (int i = 0; i < 4; i++)
#pragma unroll
      for (int j = 0; j < 4; j++) acc[m][i][j] = fz;

  const unsigned short* xb = xT + (size_t)b * 4194304;
  for (int k0 = 0; k0 < 256; k0 += 64) {
    __syncthreads();
    for (int p = tid; p < 1024; p += 256) {
      int sel = p >> 9, row = (p >> 3) & 63, j = p & 7;
      int m0 = sel * 256 + y * 64;
      uint4 v = *(const uint4*)(Wqv + (size_t)(m0 + row) * 256 + k0 + j * 8);
      *(uint4*)&As[sel][sw(row, j * 8)] = v;
    }
    for (int p = tid; p < 2048; p += 256) {
      int px = p >> 3, j = p & 7;
      uint4 v = *(const uint4*)(xb + (size_t)(n0 + px) * 256 + k0 + j * 8);
      *(uint4*)&Bs[sw(px, j * 8)] = v;
    }
    __syncthreads();
#pragma unroll
    for (int kk = 0; kk < 2; kk++) {
      f16x8 bfr[4];
#pragma unroll
      for (int nf = 0; nf < 4; nf++)
        bfr[nf] = *(const f16x8*)&Bs[sw(w * 64 + nf * 16 + l15, kk * 32 + uq * 8)];
#pragma unroll
      for (int mh = 0; mh < 2; mh++)
#pragma unroll
        for (int mf = 0; mf < 4; mf++) {
          f16x8 afr = *(const f16x8*)&As[mh][sw(mf * 16 + l15, kk * 32 + uq * 8)];
#pragma unroll
          for (int nf = 0; nf < 4; nf++)
            acc[mh][mf][nf] = mfma16(afr, bfr[nf], acc[mh][mf][nf]);
        }
    }
  }
  // q path (mh=0)
  {
    unsigned short* qb = qout + (size_t)((h * 8 + b) * 64) * 16384;
#pragma unroll
    for (int mf = 0; mf < 4; mf++)
#pragma unroll
      for (int nf = 0; nf < 4; nf++) {
        int n = n0 + w * 64 + nf * 16 + l15;
#pragma unroll
        for (int r = 0; r < 4; r++) {
          int o = mf * 16 + 4 * uq + r;
          qb[(size_t)o * 16384 + n] = f2h(acc[0][mf][nf][r] + bq[h * 64 + o]);
        }
      }
  }
  // v path (mh=1)
  {
    unsigned short* vb = vT + (size_t)(h * 8 + b) * 16384 * 64;
#pragma unroll
    for (int mf = 0; mf < 4; mf++) {
      int p0 = mf * 16 + 4 * uq;
#pragma unroll
      for (int nf = 0; nf < 4; nf++) {
        int n = n0 + w * 64 + nf * 16 + l15;
        unsigned short t0 = f2h(acc[1][mf][nf][0] + bv[h * 64 + p0 + 0]);
        unsigned short t1 = f2h(acc[1][mf][nf][1] + bv[h * 64 + p0 + 1]);
        unsigned short t2 = f2h(acc[1][mf][nf][2] + bv[h * 64 + p0 + 2]);
        unsigned short t3 = f2h(acc[1][mf][nf][3] + bv[h * 64 + p0 + 3]);
        uint2 pk;
        pk.x = (unsigned)t0 | ((unsigned)t1 << 16);
        pk.y = (unsigned)t2 | ((unsigned)t3 << 16);
        *(uint2*)&vb[(size_t)n * 64 + p0] = pk;
      }
    }
  }
}

// ---------------- dilated 3x3 conv (keys): 4 d-spaced rows, split-buffer pipe --
// Hs[2]: halo double-buffer, staged 2 chunks ahead (counted vmcnt(7), never
// drained in-loop). Ws: weights single-buffer, staged 1 chunk ahead (L2-hot).
__global__ __launch_bounds__(256, 2) void convk(const unsigned short* __restrict__ xT,
                                                const unsigned short* __restrict__ Wkb,
                                                const float* __restrict__ bk,
                                                const unsigned short* __restrict__ zp,
                                                unsigned short* __restrict__ kout) {
  __shared__ __align__(16) unsigned short Hs[2][1792 * 8];  // 2 x 28672 B
  __shared__ __align__(16) unsigned short Ws[1280 * 8];     // 20480 B
  // bijective XCD swizzle: 1024 blocks
  int orig = (blockIdx.x & 7) * 128 + (blockIdx.x >> 3);
  int g = orig & 31, b = (orig >> 5) & 7, h = orig >> 8;
  int d = 1 << h;
  int gpd = 32 >> h;
  int s = g / gpd;
  int q0 = (g - s * gpd) * 4;   // rows y = s + (q0+r)*d, r=0..3
  int nq = 128 >> h;
  int tid = threadIdx.x, lane = tid & 63, w = tid >> 6;  // w = col-quarter
  int l31 = lane & 31, hi = lane >> 5;
  const unsigned short* xb = xT + (size_t)b * 4194304;

  f32x16 acc[2][4];
#pragma unroll
  for (int i = 0; i < 2; i++)
#pragma unroll
    for (int j = 0; j < 4; j++)
#pragma unroll
      for (int r = 0; r < 16; r++) acc[i][j][r] = 0.f;

  // ---- halo pointers: items (slot*6+plane)*144+px, 7 loads/thread, stride 32B
  const char* hptr[7];
  int hstr[7];
#pragma unroll
  for (int it = 0; it < 7; it++) {
    int p = it * 256 + tid;
    hptr[it] = (const char*)zp;
    hstr[it] = 0;
    if (p < 1728) {
      int px = p % 144;
      int sp = p / 144;
      int plane = sp % 6, slot = sp / 6;
      int q = q0 + plane - 1;
      int xc = px - d;
      bool ok = (q >= 0) & (q < nq) & (xc >= 0) & (xc < 128);
      if (ok) {
        hptr[it] = (const char*)(xb + (size_t)((s + q * d) * 128 + xc) * 256 + slot * 8);
        hstr[it] = 32;
      }
    }
  }
  // ---- weight pointers: items (t*2+slot)*64+pp, 5 loads/thread, stride 2048B
  const char* wptr[5];
  int wstr[5];
#pragma unroll
  for (int it = 0; it < 5; it++) {
    int p = it * 256 + tid;
    wptr[it] = (const char*)zp;
    wstr[it] = 0;
    if (p < 1152) {
      int pp = p & 63, ts = p >> 6;
      int t = ts >> 1, slot = ts & 1;
      wptr[it] = (const char*)(Wkb + (size_t)(((h * 9 + t) * 32 + slot) * 64 + pp) * 8);
      wstr[it] = 2048;
    }
  }

  auto HSTAGE = [&](int bufi) {
#pragma unroll
    for (int it = 0; it < 7; it++) {
      int base = it * 256 + w * 64;
      __builtin_amdgcn_global_load_lds(
          (const __attribute__((address_space(1))) void*)hptr[it],
          (__attribute__((address_space(3))) void*)&Hs[bufi][(size_t)base * 8], 16, 0, 0);
      hptr[it] += hstr[it];
    }
  };
  auto WSTAGE = [&]() {
#pragma unroll
    for (int it = 0; it < 5; it++) {
      int base = it * 256 + w * 64;
      __builtin_amdgcn_global_load_lds(
          (const __attribute__((address_space(1))) void*)wptr[it],
          (__attribute__((address_space(3))) void*)&Ws[(size_t)base * 8], 16, 0, 0);
      wptr[it] += wstr[it];
    }
  };

  HSTAGE(0);   // halo 0
  WSTAGE();    // weights 0
  HSTAGE(1);   // halo 1
#pragma unroll 1
  for (int c = 0; c < 16; c++) {
    // need halo_c + w_c done; keep halo_{c+1} (7 loads) in flight
    if (c < 15) asm volatile("s_waitcnt vmcnt(7)" ::: "memory");
    else        asm volatile("s_waitcnt vmcnt(0)" ::: "memory");
    __builtin_amdgcn_s_barrier();
    __builtin_amdgcn_sched_barrier(0);
    int bufi = c & 1;
    __builtin_amdgcn_s_setprio(1);
#pragma unroll
    for (int tx = 0; tx < 3; tx++) {
      f16x8 bfr[6];
#pragma unroll
      for (int p6 = 0; p6 < 6; p6++)
        bfr[p6] = *(const f16x8*)&Hs[bufi][((hi * 6 + p6) * 144 + w * 32 + d * tx + l31) * 8];
#pragma unroll
      for (int ty = 0; ty < 3; ty++) {
        int t = ty * 3 + tx;
        f16x8 a0 = *(const f16x8*)&Ws[((t * 2 + hi) * 64 + l31) * 8];
        f16x8 a1 = *(const f16x8*)&Ws[((t * 2 + hi) * 64 + 32 + l31) * 8];
#pragma unroll
        for (int r = 0; r < 4; r++) {
          acc[0][r] = mfma32(a0, bfr[r + ty], acc[0][r]);
          acc[1][r] = mfma32(a1, bfr[r + ty], acc[1][r]);
        }
      }
    }
    __builtin_amdgcn_s_setprio(0);
    asm volatile("s_waitcnt lgkmcnt(0)" ::: "memory");
    __builtin_amdgcn_sched_barrier(0);
    __builtin_amdgcn_s_barrier();
    __builtin_amdgcn_sched_barrier(0);
    if (c < 15) WSTAGE();        // weights c+1 into Ws (now free)
    if (c < 14) HSTAGE(bufi);    // halo c+2 into Hs[bufi] (now free)
    __builtin_amdgcn_sched_barrier(0);
  }

  // epilogue: wave w owns cols w*32..w*32+31, rows r=0..3 (y = s+(q0+r)*d)
  unsigned short* kb = kout + (size_t)((h * 8 + b) * 64) * 16384;
#pragma unroll
  for (int mo = 0; mo < 2; mo++)
#pragma unroll
    for (int r = 0; r < 4; r++) {
      int y = s + (q0 + r) * d;
#pragma unroll
      for (int reg = 0; reg < 16; reg++) {
        int p = mo * 32 + (reg & 3) + 8 * (reg >> 2) + 4 * hi;
        int x = w * 32 + l31;
        kb[(size_t)p * 16384 + y * 128 + x] = f2h(acc[mo][r][reg] + bk[h * 64 + p]);
      }
    }
}

// ---------------- scores partials: q . k^T over n-chunk of 2048 ----------------
__global__ __launch_bounds__(256) void scoresk(const unsigned short* __restrict__ qin,
                                               const unsigned short* __restrict__ kin,
                                               float* __restrict__ part) {
  __shared__ __align__(16) unsigned short As[64 * 64];
  __shared__ __align__(16) unsigned short Bs[64 * 64];
  int nch = blockIdx.x, b = blockIdx.y, h = blockIdx.z;
  int tid = threadIdx.x, lane = tid & 63, w = tid >> 6;
  int l15 = lane & 15, uq = lane >> 4;
  const unsigned short* qb = qin + (size_t)((h * 8 + b) * 64) * 16384;
  const unsigned short* kb = kin + (size_t)((h * 8 + b) * 64) * 16384;
  int moff = (w >> 1) * 32, noff = (w & 1) * 32;
  const f32x4 fz = {0.f, 0.f, 0.f, 0.f};
  f32x4 acc[2][2] = {{fz, fz}, {fz, fz}};
  for (int ci = 0; ci < 32; ci++) {
    int nb = nch * 2048 + ci * 64;
    __syncthreads();
    for (int p = tid; p < 512; p += 256) {
      int row = p >> 3, j = p & 7;
      *(uint4*)&As[sw(row, j * 8)] = *(const uint4*)(qb + (size_t)row * 16384 + nb + j * 8);
      *(uint4*)&Bs[sw(row, j * 8)] = *(const uint4*)(kb + (size_t)row * 16384 + nb + j * 8);
    }
    __syncthreads();
#pragma unroll
    for (int kk = 0; kk < 2; kk++) {
      f16x8 b0 = *(const f16x8*)&Bs[sw(noff + l15, kk * 32 + uq * 8)];
      f16x8 b1 = *(const f16x8*)&Bs[sw(noff + 16 + l15, kk * 32 + uq * 8)];
      f16x8 a0 = *(const f16x8*)&As[sw(moff + l15, kk * 32 + uq * 8)];
      f16x8 a1 = *(const f16x8*)&As[sw(moff + 16 + l15, kk * 32 + uq * 8)];
      acc[0][0] = mfma16(a0, b0, acc[0][0]);
      acc[0][1] = mfma16(a0, b1, acc[0][1]);
      acc[1][0] = mfma16(a1, b0, acc[1][0]);
      acc[1][1] = mfma16(a1, b1, acc[1][1]);
    }
  }
  float* pb = part + (size_t)((nch * 4 + h) * 8 + b) * 4096;
#pragma unroll
  for (int mf = 0; mf < 2; mf++)
#pragma unroll
    for (int nf = 0; nf < 2; nf++) {
      int p = noff + nf * 16 + l15;
#pragma unroll
      for (int r = 0; r < 4; r++) {
        int o = moff + mf * 16 + 4 * uq + r;
        pb[o * 64 + p] = acc[mf][nf][r];
      }
    }
}

// ---------------- softmax over p (one wave per (h,b,o) row) ----------------
__global__ __launch_bounds__(256) void smax(const float* __restrict__ part,
                                            unsigned short* __restrict__ attn) {
  int row = blockIdx.x * 4 + (threadIdx.x >> 6);
  int lane = threadIdx.x & 63;
  int h = row >> 9, b = (row >> 6) & 7, o = row & 63;
  float s = 0.f;
#pragma unroll
  for (int nch = 0; nch < 8; nch++)
    s += part[(size_t)((nch * 4 + h) * 8 + b) * 4096 + o * 64 + lane];
  s *= 0.0625f;  // 1/sqrt(256)
  float m = s;
#pragma unroll
  for (int k = 32; k > 0; k >>= 1) m = fmaxf(m, __shfl_xor(m, k, 64));
  float e = __expf(s - m);
  float sum = e;
#pragma unroll
  for (int k = 32; k > 0; k >>= 1) sum += __shfl_xor(sum, k, 64);
  attn[(size_t)(h * 8 + b) * 4096 + o * 64 + lane] = f2h(e / sum);
}

// ---------------- out = attn @ v ----------------
__global__ __launch_bounds__(256) void outk(const unsigned short* __restrict__ attn,
                                            const unsigned short* __restrict__ vT,
                                            float* __restrict__ out) {
  __shared__ __align__(16) unsigned short As[64 * 64];
  __shared__ __align__(16) unsigned short Bs[256 * 64];
  int n0 = blockIdx.x * 256, b = blockIdx.y, h = blockIdx.z;
  int tid = threadIdx.x, lane = tid & 63, w = tid >> 6;
  int l15 = lane & 15, uq = lane >> 4;
  const unsigned short* ab = attn + (size_t)(h * 8 + b) * 4096;
  const unsigned short* vb = vT + (size_t)(h * 8 + b) * 16384 * 64;
  for (int p = tid; p < 512; p += 256) {
    int row = p >> 3, j = p & 7;
    *(uint4*)&As[sw(row, j * 8)] = *(const uint4*)(ab + row * 64 + j * 8);
  }
  for (int p = tid; p < 2048; p += 256) {
    int px = p >> 3, j = p & 7;
    *(uint4*)&Bs[sw(px, j * 8)] = *(const uint4*)(vb + (size_t)(n0 + px) * 64 + j * 8);
  }
  __syncthreads();
  const f32x4 fz = {0.f, 0.f, 0.f, 0.f};
  f32x4 acc[4][4];
#pragma unroll
  for (int i = 0; i < 4; i++)
#pragma unroll
    for (int j = 0; j < 4; j++) acc[i][j] = fz;
#pragma unroll
  for (int kk = 0; kk < 2; kk++) {
    f16x8 bfr[4];
#pragma unroll
    for (int nf = 0; nf < 4; nf++)
      bfr[nf] = *(const f16x8*)&Bs[sw(w * 64 + nf * 16 + l15, kk * 32 + uq * 8)];
#pragma unroll
    for (int mf = 0; mf < 4; mf++) {
      f16x8 afr = *(const f16x8*)&As[sw(mf * 16 + l15, kk * 32 + uq * 8)];
#pragma unroll
      for (int nf = 0; nf < 4; nf++) acc[mf][nf] = mfma16(afr, bfr[nf], acc[mf][nf]);
    }
  }
  float* ob = out + (size_t)b * 4194304 + (size_t)(h * 64) * 16384;
#pragma unroll
  for (int mf = 0; mf < 4; mf++)
#pragma unroll
    for (int nf = 0; nf < 4; nf++) {
      int n = n0 + w * 64 + nf * 16 + l15;
#pragma unroll
      for (int r = 0; r < 4; r++) {
        int o = mf * 16 + 4 * uq + r;
        ob[(size_t)o * 16384 + n] = acc[mf][nf][r];
      }
    }
}

extern "C" void kernel_launch(void* const* d_in, const int* in_sizes, int n_in,
                              void* d_out, int out_size, void* d_ws, size_t ws_size,
                              hipStream_t stream) {
  const float* x  = (const float*)d_in[0];
  const float* Wq = (const float*)d_in[1];
  const float* bq = (const float*)d_in[2];
  const float* Wk = (const float*)d_in[3];
  const float* bk = (const float*)d_in[4];
  const float* Wv = (const float*)d_in[5];
  const float* bv = (const float*)d_in[6];
  float* out = (float*)d_out;

  char* ws = (char*)d_ws;
  unsigned short* kbuf = (unsigned short*)(ws);
  unsigned short* vT   = (unsigned short*)(ws + 67108864);
  unsigned short* attn = (unsigned short*)(ws + 134217728);
  unsigned short* Wqv  = (unsigned short*)(ws + 134479872);
  unsigned short* Wkb  = (unsigned short*)(ws + 134742016);
  unsigned short* zp   = (unsigned short*)(ws + 135921664);
  // d_out doubles as scratch: xT in first half, q in second; part reuses dead xT.
  unsigned short* xT = (unsigned short*)d_out;
  unsigned short* qb = (unsigned short*)d_out + 33554432;
  float* part = (float*)d_out;

  prep<<<dim3(2816), dim3(256), 0, stream>>>(Wq, Wv, Wk, Wqv, Wkb, zp);
  xpose<<<dim3(256, 4, 8), dim3(256), 0, stream>>>(x, xT);
  proj<<<dim3(64, 4, 8), dim3(256), 0, stream>>>(xT, Wqv, bq, bv, qb, vT);
  convk<<<dim3(1024), dim3(256), 0, stream>>>(xT, Wkb, bk, zp, kbuf);
  scoresk<<<dim3(8, 8, 4), dim3(256), 0, stream>>>(qb, kbuf, part);
  smax<<<dim3(512), dim3(256), 0, stream>>>(part, attn);
  outk<<<dim3(64, 8, 4), dim3(256), 0, stream>>>(attn, vT, out);
}

// Round 11
// 412.071 us; speedup vs baseline: 1.0536x; 1.0536x over previous
//
#include <hip/hip_runtime.h>
#include <hip/hip_bf16.h>

// Channel attention (4 heads, dilated 3x3 key convs d=1,2,4,8), f16 MFMA pipeline.
// R11: convk -- 64-col x 4-row blocks, acc 64 AGPR, 50KB LDS, launch_bounds(256,3)
// -> 3 blocks/CU; uniform counted vmcnt(3). proj -- x staged ONCE per (n-tile,b),
// Wqvn A-frag-native read from L2 (no weight LDS), all 16 m-tiles per block.
//
// ws layout (bytes):
//   kbuf : [0,           67108864)   k  f16 [h][b][p][n]
//   vT   : [67108864,   134217728)   v  f16 [h][b][n][p]   (pixel-major)
//   attn : [134217728,  134479872)   attn f16 [h][b][o][p]
//   Wqvn : [134479872,  134742016)   f16 A-frag-native [mt16][ks16][hi2][m32][8]
//   Wkb  : [134742016,  135921664)   f16 [h][t][ks32][p64][8]  (MFMA A-frag native)
//   zpage: [135921664,  135922176)   zeros (OOB load source, 512 B)
// d_out reused as scratch (dead before final kernel):
//   xT   : bytes [0, 64Mi)   f16 [b][n][c]
//   q    : bytes [64Mi,128Mi) f16 [h][b][o][n]
//   part : bytes [0, 4Mi)    fp32 partial scores (written AFTER conv, xT dead)

typedef __attribute__((ext_vector_type(8))) _Float16 f16x8;
typedef __attribute__((ext_vector_type(4))) float f32x4;
typedef __attribute__((ext_vector_type(16))) float f32x16;

__device__ __forceinline__ unsigned short f2h(float f) {
  union { _Float16 h; unsigned short u; } v;
  v.h = (_Float16)f;
  return v.u;
}

__device__ __forceinline__ f32x4 mfma16(f16x8 a, f16x8 b, f32x4 c) {
  return __builtin_amdgcn_mfma_f32_16x16x32_f16(a, b, c, 0, 0, 0);
}
__device__ __forceinline__ f32x16 mfma32(f16x8 a, f16x8 b, f32x16 c) {
  return __builtin_amdgcn_mfma_f32_32x32x16_f16(a, b, c, 0, 0, 0);
}

// swizzled index into a [R][64]-ushort tile (128B rows): XOR bits 4..6 of byte off
__device__ __forceinline__ int sw(int row, int c) {
  return row * 64 + ((((c << 1) ^ ((row & 7) << 4)) >> 1));
}

// ---------------- weight prep ----------------
__global__ __launch_bounds__(256) void prep(const float* __restrict__ Wq,
                                            const float* __restrict__ Wv,
                                            const float* __restrict__ Wk,
                                            unsigned short* __restrict__ Wqvn,
                                            unsigned short* __restrict__ Wkb,
                                            unsigned short* __restrict__ zp) {
  int i = blockIdx.x * 256 + threadIdx.x;
  if (blockIdx.x == 0) zp[threadIdx.x] = 0;  // 512 B zero page
  const int total = 131072 + 589824;
  if (i >= total) return;
  if (i < 131072) {
    // Wqvn[(((mt*16+ks)*2+hi)*32 + m31)*8 + jj] = W[row=mt*32+m31][ch=ks*16+hi*8+jj]
    int jj = i & 7;
    int m31 = (i >> 3) & 31;
    int hi = (i >> 8) & 1;
    int ks = (i >> 9) & 15;
    int mt = i >> 13;
    int row = mt * 32 + m31;
    int ch = ks * 16 + hi * 8 + jj;
    Wqvn[i] = f2h(row < 256 ? Wq[row * 256 + ch] : Wv[(row - 256) * 256 + ch]);
  } else {
    int j = i - 131072;  // (((h*9+t)*32 + ks)*64 + p)*8 + jj
    int jj = j & 7;
    int p = (j >> 3) & 63;
    int ks = (j >> 9) & 31;
    int ht = j >> 14;
    int t = ht % 9;
    int h = ht / 9;
    Wkb[j] = f2h(Wk[(size_t)((h * 64 + p) * 256 + ks * 8 + jj) * 9 + t]);
  }
}

// ---------------- x (b,c,n) fp32 -> xT (b,n,c) f16 ----------------
__global__ __launch_bounds__(256) void xpose(const float* __restrict__ x,
                                             unsigned short* __restrict__ xT) {
  __shared__ unsigned short tile[64][66];
  int n0 = blockIdx.x * 64, c0 = blockIdx.y * 64, b = blockIdx.z;
  int t = threadIdx.x;
  int r = t >> 2, q = t & 3;
  const float* src = x + (size_t)b * 4194304 + (size_t)(c0 + r) * 16384 + n0 + q * 16;
#pragma unroll
  for (int i = 0; i < 4; i++) {
    float4 v = *(const float4*)(src + i * 4);
    tile[r][q * 16 + i * 4 + 0] = f2h(v.x);
    tile[r][q * 16 + i * 4 + 1] = f2h(v.y);
    tile[r][q * 16 + i * 4 + 2] = f2h(v.z);
    tile[r][q * 16 + i * 4 + 3] = f2h(v.w);
  }
  __syncthreads();
  int c = t & 63, pq = t >> 6;
  unsigned short* dst = xT + (size_t)b * 4194304 + (size_t)n0 * 256 + c0 + c;
#pragma unroll
  for (int i = 0; i < 16; i++) {
    int px = i * 4 + pq;
    dst[(size_t)px * 256] = tile[c][px];
  }
}

// ---------------- Q/V projection: x staged once, Wqvn from L2 -----------------
// Block = (64 px, batch). Xs [64 px][32 granules] with g^(px&31) swizzle (src
// pre-swizzled for global_load_lds). 16 m-tiles (8 q + 8 v) per block; wave w
// owns m-tiles w*4..w*4+3 (waves 0,1 = q; 2,3 = v), 2 n-tiles of 32 px.
__global__ __launch_bounds__(256) void proj(const unsigned short* __restrict__ xT,
                                            const unsigned short* __restrict__ Wqvn,
                                            const float* __restrict__ bq,
                                            const float* __restrict__ bv,
                                            unsigned short* __restrict__ qout,
                                            unsigned short* __restrict__ vT) {
  __shared__ __align__(16) unsigned short Xs[2048 * 8];  // 32 KB
  int n0 = blockIdx.x * 64, b = blockIdx.y;
  int tid = threadIdx.x, lane = tid & 63, w = tid >> 6;
  int l31 = lane & 31, hi = lane >> 5;
  const unsigned short* xb = xT + (size_t)b * 4194304;
  // stage x-tile: 2048 granules of 16B, source channel-granule pre-swizzled
#pragma unroll
  for (int it = 0; it < 8; it++) {
    int base = it * 256 + w * 64;
    int p = base + lane;
    int px = p >> 5, g = p & 31;
    int gs = g ^ (px & 31);
    const unsigned short* gsrc = xb + (size_t)(n0 + px) * 256 + gs * 8;
    __builtin_amdgcn_global_load_lds(
        (const __attribute__((address_space(1))) void*)gsrc,
        (__attribute__((address_space(3))) void*)&Xs[(size_t)base * 8], 16, 0, 0);
  }
  __syncthreads();

  f32x16 acc[4][2];
#pragma unroll
  for (int i = 0; i < 4; i++)
#pragma unroll
    for (int j = 0; j < 2; j++)
#pragma unroll
      for (int r = 0; r < 16; r++) acc[i][j][r] = 0.f;

#pragma unroll
  for (int ks = 0; ks < 16; ks++) {
    f16x8 bfr[2];
#pragma unroll
    for (int nt = 0; nt < 2; nt++) {
      int px = nt * 32 + l31;
      int gl = (ks * 2 + hi) ^ (px & 31);
      bfr[nt] = *(const f16x8*)&Xs[(px * 32 + gl) * 8];
    }
#pragma unroll
    for (int mj = 0; mj < 4; mj++) {
      int mt = w * 4 + mj;
      f16x8 afr = *(const f16x8*)(Wqvn + (size_t)(((mt * 16 + ks) * 2 + hi) * 32 + l31) * 8);
      acc[mj][0] = mfma32(afr, bfr[0], acc[mj][0]);
      acc[mj][1] = mfma32(afr, bfr[1], acc[mj][1]);
    }
  }

  if (w < 2) {  // q path: og = mt*32 + row
#pragma unroll
    for (int mj = 0; mj < 4; mj++) {
      int mt = w * 4 + mj;
#pragma unroll
      for (int nt = 0; nt < 2; nt++) {
        int n = n0 + nt * 32 + l31;
#pragma unroll
        for (int r = 0; r < 16; r++) {
          int og = mt * 32 + (r & 3) + 8 * (r >> 2) + 4 * hi;
          int h = og >> 6, o = og & 63;
          qout[((size_t)(h * 8 + b) * 64 + o) * 16384 + n] = f2h(acc[mj][nt][r] + bq[og]);
        }
      }
    }
  } else {  // v path: pg = (mt-8)*32 + row; packed uint2 (4 consecutive p)
#pragma unroll
    for (int mj = 0; mj < 4; mj++) {
      int mt = w * 4 + mj;
#pragma unroll
      for (int nt = 0; nt < 2; nt++) {
        int n = n0 + nt * 32 + l31;
#pragma unroll
        for (int rq = 0; rq < 4; rq++) {
          int pgb = (mt - 8) * 32 + 8 * rq + 4 * hi;
          int h = pgb >> 6, p = pgb & 63;
          unsigned short t0 = f2h(acc[mj][nt][rq * 4 + 0] + bv[pgb + 0]);
          unsigned short t1 = f2h(acc[mj][nt][rq * 4 + 1] + bv[pgb + 1]);
          unsigned short t2 = f2h(acc[mj][nt][rq * 4 + 2] + bv[pgb + 2]);
          unsigned short t3 = f2h(acc[mj][nt][rq * 4 + 3] + bv[pgb + 3]);
          uint2 pk;
          pk.x = (unsigned)t0 | ((unsigned)t1 << 16);
          pk.y = (unsigned)t2 | ((unsigned)t3 << 16);
          *(uint2*)&vT[((size_t)(h * 8 + b) * 16384 + n) * 64 + p] = pk;
        }
      }
    }
  }
}

// ---------------- dilated 3x3 conv (keys): 4 rows x 64 cols, 3 blocks/CU ------
// Hs[2] halo (80px x 6 planes x 2 kslots, 16KB each), Ws weights (18KB).
// Waves = (outch-half, col-half); acc 64 AGPR. Uniform vmcnt(3) counted pipe.
__global__ __launch_bounds__(256, 3) void convk(const unsigned short* __restrict__ xT,
                                                const unsigned short* __restrict__ Wkb,
                                                const float* __restrict__ bk,
                                                const unsigned short* __restrict__ zp,
                                                unsigned short* __restrict__ kout) {
  __shared__ __align__(16) unsigned short Hs[2][1024 * 8];  // 2 x 16 KB
  __shared__ __align__(16) unsigned short Ws[1152 * 8];     // 18 KB
  // bijective XCD swizzle: 2048 blocks
  int orig = (blockIdx.x & 7) * 256 + (blockIdx.x >> 3);
  int ct = orig & 1;
  int g = (orig >> 1) & 31;
  int b = (orig >> 6) & 7;
  int h = orig >> 9;
  int d = 1 << h;
  int gpd = 32 >> h;
  int s = g / gpd;
  int q0 = (g - s * gpd) * 4;   // rows y = s + (q0+r)*d, r=0..3
  int nq = 128 >> h;
  int tid = threadIdx.x, lane = tid & 63, w = tid >> 6;
  int l31 = lane & 31, hi = lane >> 5;
  int wc = w & 1, mo = w >> 1;  // col-half, outch-half
  const unsigned short* xb = xT + (size_t)b * 4194304;

  f32x16 acc[4];
#pragma unroll
  for (int j = 0; j < 4; j++)
#pragma unroll
    for (int r = 0; r < 16; r++) acc[j][r] = 0.f;

  // halo items [0,960): (slot*6+plane)*80+px ; stride 32 B/chunk; OOB walk zp
  const char* hptr[4];
#pragma unroll
  for (int it = 0; it < 4; it++) {
    int p = it * 256 + tid;
    hptr[it] = (const char*)zp;
    if (p < 960) {
      int px = p % 80;
      int sp = p / 80;
      int plane = sp % 6, slot = sp / 6;
      int q = q0 + plane - 1;
      int xc = ct * 64 + px - d;
      if (q >= 0 && q < nq && xc >= 0 && xc < 128)
        hptr[it] = (const char*)(xb + (size_t)((s + q * d) * 128 + xc) * 256 + slot * 8);
    }
  }
  // weight items [0,1152): (t*2+slot)*64+pp ; stride 2048 B/chunk
  const char* wptr[5];
#pragma unroll
  for (int it = 0; it < 5; it++) {
    int p = it * 256 + tid;
    wptr[it] = (const char*)zp;
    if (p < 1152) {
      int pp = p & 63, ts = p >> 6;
      int t = ts >> 1, slot = ts & 1;
      wptr[it] = (const char*)(Wkb + (size_t)(((h * 9 + t) * 32 + slot) * 64 + pp) * 8);
    }
  }

  auto HSTAGE = [&](int bufi) {
#pragma unroll
    for (int it = 0; it < 4; it++) {
      int base = it * 256 + w * 64;
      if (base < 960) {  // wave-uniform (it=3,w=3 skipped)
        __builtin_amdgcn_global_load_lds(
            (const __attribute__((address_space(1))) void*)hptr[it],
            (__attribute__((address_space(3))) void*)&Hs[bufi][(size_t)base * 8], 16, 0, 0);
        hptr[it] += 32;
      }
    }
  };
  auto WSTAGE = [&]() {
#pragma unroll
    for (int it = 0; it < 5; it++) {
      int base = it * 256 + w * 64;
      if (base < 1152) {  // wave-uniform (it=4,w>=2 skipped)
        __builtin_amdgcn_global_load_lds(
            (const __attribute__((address_space(1))) void*)wptr[it],
            (__attribute__((address_space(3))) void*)&Ws[(size_t)base * 8], 16, 0, 0);
        wptr[it] += 2048;
      }
    }
  };

  HSTAGE(0);   // halo 0
  WSTAGE();    // weights 0
  HSTAGE(1);   // halo 1
#pragma unroll 1
  for (int c = 0; c < 16; c++) {
    // retire {H_c leftovers, W_c}; keep newest 3 (tail of H_{c+1}) in flight
    if (c < 15) asm volatile("s_waitcnt vmcnt(3)" ::: "memory");
    else        asm volatile("s_waitcnt vmcnt(0)" ::: "memory");
    __builtin_amdgcn_s_barrier();
    __builtin_amdgcn_sched_barrier(0);
    int bufi = c & 1;
    __builtin_amdgcn_s_setprio(1);
#pragma unroll
    for (int tx = 0; tx < 3; tx++) {
      f16x8 bfr[6];
#pragma unroll
      for (int p6 = 0; p6 < 6; p6++)
        bfr[p6] = *(const f16x8*)&Hs[bufi][((hi * 6 + p6) * 80 + wc * 32 + d * tx + l31) * 8];
#pragma unroll
      for (int ty = 0; ty < 3; ty++) {
        int t = ty * 3 + tx;
        f16x8 a = *(const f16x8*)&Ws[((t * 2 + hi) * 64 + mo * 32 + l31) * 8];
#pragma unroll
        for (int r = 0; r < 4; r++)
          acc[r] = mfma32(a, bfr[r + ty], acc[r]);
      }
    }
    __builtin_amdgcn_s_setprio(0);
    asm volatile("s_waitcnt lgkmcnt(0)" ::: "memory");
    __builtin_amdgcn_sched_barrier(0);
    __builtin_amdgcn_s_barrier();
    __builtin_amdgcn_sched_barrier(0);
    if (c < 15) WSTAGE();        // weights c+1
    if (c < 14) HSTAGE(bufi);    // halo c+2
    __builtin_amdgcn_sched_barrier(0);
  }

  // epilogue: wave (mo,wc): p = mo*32+row, x = ct*64 + wc*32 + l31
  unsigned short* kb = kout + (size_t)((h * 8 + b) * 64) * 16384;
  int x = ct * 64 + wc * 32 + l31;
#pragma unroll
  for (int r = 0; r < 4; r++) {
    int y = s + (q0 + r) * d;
#pragma unroll
    for (int reg = 0; reg < 16; reg++) {
      int p = mo * 32 + (reg & 3) + 8 * (reg >> 2) + 4 * hi;
      kb[(size_t)p * 16384 + y * 128 + x] = f2h(acc[r][reg] + bk[h * 64 + p]);
    }
  }
}

// ---------------- scores partials: q . k^T over n-chunk of 2048 ----------------
__global__ __launch_bounds__(256) void scoresk(const unsigned short* __restrict__ qin,
                                               const unsigned short* __restrict__ kin,
                                               float* __restrict__ part) {
  __shared__ __align__(16) unsigned short As[64 * 64];
  __shared__ __align__(16) unsigned short Bs[64 * 64];
  int nch = blockIdx.x, b = blockIdx.y, h = blockIdx.z;
  int tid = threadIdx.x, lane = tid & 63, w = tid >> 6;
  int l15 = lane & 15, uq = lane >> 4;
  const unsigned short* qb = qin + (size_t)((h * 8 + b) * 64) * 16384;
  const unsigned short* kb = kin + (size_t)((h * 8 + b) * 64) * 16384;
  int moff = (w >> 1) * 32, noff = (w & 1) * 32;
  const f32x4 fz = {0.f, 0.f, 0.f, 0.f};
  f32x4 acc[2][2] = {{fz, fz}, {fz, fz}};
  for (int ci = 0; ci < 32; ci++) {
    int nb = nch * 2048 + ci * 64;
    __syncthreads();
    for (int p = tid; p < 512; p += 256) {
      int row = p >> 3, j = p & 7;
      *(uint4*)&As[sw(row, j * 8)] = *(const uint4*)(qb + (size_t)row * 16384 + nb + j * 8);
      *(uint4*)&Bs[sw(row, j * 8)] = *(const uint4*)(kb + (size_t)row * 16384 + nb + j * 8);
    }
    __syncthreads();
#pragma unroll
    for (int kk = 0; kk < 2; kk++) {
      f16x8 b0 = *(const f16x8*)&Bs[sw(noff + l15, kk * 32 + uq * 8)];
      f16x8 b1 = *(const f16x8*)&Bs[sw(noff + 16 + l15, kk * 32 + uq * 8)];
      f16x8 a0 = *(const f16x8*)&As[sw(moff + l15, kk * 32 + uq * 8)];
      f16x8 a1 = *(const f16x8*)&As[sw(moff + 16 + l15, kk * 32 + uq * 8)];
      acc[0][0] = mfma16(a0, b0, acc[0][0]);
      acc[0][1] = mfma16(a0, b1, acc[0][1]);
      acc[1][0] = mfma16(a1, b0, acc[1][0]);
      acc[1][1] = mfma16(a1, b1, acc[1][1]);
    }
  }
  float* pb = part + (size_t)((nch * 4 + h) * 8 + b) * 4096;
#pragma unroll
  for (int mf = 0; mf < 2; mf++)
#pragma unroll
    for (int nf = 0; nf < 2; nf++) {
      int p = noff + nf * 16 + l15;
#pragma unroll
      for (int r = 0; r < 4; r++) {
        int o = moff + mf * 16 + 4 * uq + r;
        pb[o * 64 + p] = acc[mf][nf][r];
      }
    }
}

// ---------------- softmax over p (one wave per (h,b,o) row) ----------------
__global__ __launch_bounds__(256) void smax(const float* __restrict__ part,
                                            unsigned short* __restrict__ attn) {
  int row = blockIdx.x * 4 + (threadIdx.x >> 6);
  int lane = threadIdx.x & 63;
  int h = row >> 9, b = (row >> 6) & 7, o = row & 63;
  float s = 0.f;
#pragma unroll
  for (int nch = 0; nch < 8; nch++)
    s += part[(size_t)((nch * 4 + h) * 8 + b) * 4096 + o * 64 + lane];
  s *= 0.0625f;  // 1/sqrt(256)
  float m = s;
#pragma unroll
  for (int k = 32; k > 0; k >>= 1) m = fmaxf(m, __shfl_xor(m, k, 64));
  float e = __expf(s - m);
  float sum = e;
#pragma unroll
  for (int k = 32; k > 0; k >>= 1) sum += __shfl_xor(sum, k, 64);
  attn[(size_t)(h * 8 + b) * 4096 + o * 64 + lane] = f2h(e / sum);
}

// ---------------- out = attn @ v ----------------
__global__ __launch_bounds__(256) void outk(const unsigned short* __restrict__ attn,
                                            const unsigned short* __restrict__ vT,
                                            float* __restrict__ out) {
  __shared__ __align__(16) unsigned short As[64 * 64];
  __shared__ __align__(16) unsigned short Bs[256 * 64];
  int n0 = blockIdx.x * 256, b = blockIdx.y, h = blockIdx.z;
  int tid = threadIdx.x, lane = tid & 63, w = tid >> 6;
  int l15 = lane & 15, uq = lane >> 4;
  const unsigned short* ab = attn + (size_t)(h * 8 + b) * 4096;
  const unsigned short* vb = vT + (size_t)(h * 8 + b) * 16384 * 64;
  for (int p = tid; p < 512; p += 256) {
    int row = p >> 3, j = p & 7;
    *(uint4*)&As[sw(row, j * 8)] = *(const uint4*)(ab + row * 64 + j * 8);
  }
  for (int p = tid; p < 2048; p += 256) {
    int px = p >> 3, j = p & 7;
    *(uint4*)&Bs[sw(px, j * 8)] = *(const uint4*)(vb + (size_t)(n0 + px) * 64 + j * 8);
  }
  __syncthreads();
  const f32x4 fz = {0.f, 0.f, 0.f, 0.f};
  f32x4 acc[4][4];
#pragma unroll
  for (int i = 0; i < 4; i++)
#pragma unroll
    for (int j = 0; j < 4; j++) acc[i][j] = fz;
#pragma unroll
  for (int kk = 0; kk < 2; kk++) {
    f16x8 bfr[4];
#pragma unroll
    for (int nf = 0; nf < 4; nf++)
      bfr[nf] = *(const f16x8*)&Bs[sw(w * 64 + nf * 16 + l15, kk * 32 + uq * 8)];
#pragma unroll
    for (int mf = 0; mf < 4; mf++) {
      f16x8 afr = *(const f16x8*)&As[sw(mf * 16 + l15, kk * 32 + uq * 8)];
#pragma unroll
      for (int nf = 0; nf < 4; nf++) acc[mf][nf] = mfma16(afr, bfr[nf], acc[mf][nf]);
    }
  }
  float* ob = out + (size_t)b * 4194304 + (size_t)(h * 64) * 16384;
#pragma unroll
  for (int mf = 0; mf < 4; mf++)
#pragma unroll
    for (int nf = 0; nf < 4; nf++) {
      int n = n0 + w * 64 + nf * 16 + l15;
#pragma unroll
      for (int r = 0; r < 4; r++) {
        int o = mf * 16 + 4 * uq + r;
        ob[(size_t)o * 16384 + n] = acc[mf][nf][r];
      }
    }
}

extern "C" void kernel_launch(void* const* d_in, const int* in_sizes, int n_in,
                              void* d_out, int out_size, void* d_ws, size_t ws_size,
                              hipStream_t stream) {
  const float* x  = (const float*)d_in[0];
  const float* Wq = (const float*)d_in[1];
  const float* bq = (const float*)d_in[2];
  const float* Wk = (const float*)d_in[3];
  const float* bk = (const float*)d_in[4];
  const float* Wv = (const float*)d_in[5];
  const float* bv = (const float*)d_in[6];
  float* out = (float*)d_out;

  char* ws = (char*)d_ws;
  unsigned short* kbuf = (unsigned short*)(ws);
  unsigned short* vT   = (unsigned short*)(ws + 67108864);
  unsigned short* attn = (unsigned short*)(ws + 134217728);
  unsigned short* Wqvn = (unsigned short*)(ws + 134479872);
  unsigned short* Wkb  = (unsigned short*)(ws + 134742016);
  unsigned short* zp   = (unsigned short*)(ws + 135921664);
  // d_out doubles as scratch: xT in first half, q in second; part reuses dead xT.
  unsigned short* xT = (unsigned short*)d_out;
  unsigned short* qb = (unsigned short*)d_out + 33554432;
  float* part = (float*)d_out;

  prep<<<dim3(2816), dim3(256), 0, stream>>>(Wq, Wv, Wk, Wqvn, Wkb, zp);
  xpose<<<dim3(256, 4, 8), dim3(256), 0, stream>>>(x, xT);
  proj<<<dim3(256, 8), dim3(256), 0, stream>>>(xT, Wqvn, bq, bv, qb, vT);
  convk<<<dim3(2048), dim3(256), 0, stream>>>(xT, Wkb, bk, zp, kbuf);
  scoresk<<<dim3(8, 8, 4), dim3(256), 0, stream>>>(qb, kbuf, part);
  smax<<<dim3(512), dim3(256), 0, stream>>>(part, attn);
  outk<<<dim3(64, 8, 4), dim3(256), 0, stream>>>(attn, vT, out);
}

// Round 12
// 406.100 us; speedup vs baseline: 1.0691x; 1.0147x over previous
//
#include <hip/hip_runtime.h>
#include <hip/hip_bf16.h>

// Channel attention (4 heads, dilated 3x3 key convs d=1,2,4,8), f16 MFMA pipeline.
// R12: convk reverted to R10 (best measured, 176us). proj: v output transposed
// through LDS -> coalesced 128B-row stores (was 16x store amplification).
// outk: staging via global_load_lds with pre-swizzled source.
//
// ws layout (bytes):
//   kbuf : [0,           67108864)   k  f16 [h][b][p][n]
//   vT   : [67108864,   134217728)   v  f16 [h][b][n][p]   (pixel-major)
//   attn : [134217728,  134479872)   attn f16 [h][b][o][p]
//   Wqvn : [134479872,  134742016)   f16 A-frag-native [mt16][ks16][hi2][m32][8]
//   Wkb  : [134742016,  135921664)   f16 [h][t][ks32][p64][8]  (MFMA A-frag native)
//   zpage: [135921664,  135922176)   zeros (OOB load source, 512 B)
// d_out reused as scratch (dead before final kernel):
//   xT   : bytes [0, 64Mi)   f16 [b][n][c]
//   q    : bytes [64Mi,128Mi) f16 [h][b][o][n]
//   part : bytes [0, 4Mi)    fp32 partial scores (written AFTER conv, xT dead)

typedef __attribute__((ext_vector_type(8))) _Float16 f16x8;
typedef __attribute__((ext_vector_type(4))) float f32x4;
typedef __attribute__((ext_vector_type(16))) float f32x16;

__device__ __forceinline__ unsigned short f2h(float f) {
  union { _Float16 h; unsigned short u; } v;
  v.h = (_Float16)f;
  return v.u;
}

__device__ __forceinline__ f32x4 mfma16(f16x8 a, f16x8 b, f32x4 c) {
  return __builtin_amdgcn_mfma_f32_16x16x32_f16(a, b, c, 0, 0, 0);
}
__device__ __forceinline__ f32x16 mfma32(f16x8 a, f16x8 b, f32x16 c) {
  return __builtin_amdgcn_mfma_f32_32x32x16_f16(a, b, c, 0, 0, 0);
}

// swizzled index into a [R][64]-ushort tile (128B rows): XOR bits 4..6 of byte off
__device__ __forceinline__ int sw(int row, int c) {
  return row * 64 + ((((c << 1) ^ ((row & 7) << 4)) >> 1));
}

// ---------------- weight prep ----------------
__global__ __launch_bounds__(256) void prep(const float* __restrict__ Wq,
                                            const float* __restrict__ Wv,
                                            const float* __restrict__ Wk,
                                            unsigned short* __restrict__ Wqvn,
                                            unsigned short* __restrict__ Wkb,
                                            unsigned short* __restrict__ zp) {
  int i = blockIdx.x * 256 + threadIdx.x;
  if (blockIdx.x == 0) zp[threadIdx.x] = 0;  // 512 B zero page
  const int total = 131072 + 589824;
  if (i >= total) return;
  if (i < 131072) {
    // Wqvn[(((mt*16+ks)*2+hi)*32 + m31)*8 + jj] = W[row=mt*32+m31][ch=ks*16+hi*8+jj]
    int jj = i & 7;
    int m31 = (i >> 3) & 31;
    int hi = (i >> 8) & 1;
    int ks = (i >> 9) & 15;
    int mt = i >> 13;
    int row = mt * 32 + m31;
    int ch = ks * 16 + hi * 8 + jj;
    Wqvn[i] = f2h(row < 256 ? Wq[row * 256 + ch] : Wv[(row - 256) * 256 + ch]);
  } else {
    int j = i - 131072;  // (((h*9+t)*32 + ks)*64 + p)*8 + jj
    int jj = j & 7;
    int p = (j >> 3) & 63;
    int ks = (j >> 9) & 31;
    int ht = j >> 14;
    int t = ht % 9;
    int h = ht / 9;
    Wkb[j] = f2h(Wk[(size_t)((h * 64 + p) * 256 + ks * 8 + jj) * 9 + t]);
  }
}

// ---------------- x (b,c,n) fp32 -> xT (b,n,c) f16 ----------------
__global__ __launch_bounds__(256) void xpose(const float* __restrict__ x,
                                             unsigned short* __restrict__ xT) {
  __shared__ unsigned short tile[64][66];
  int n0 = blockIdx.x * 64, c0 = blockIdx.y * 64, b = blockIdx.z;
  int t = threadIdx.x;
  int r = t >> 2, q = t & 3;
  const float* src = x + (size_t)b * 4194304 + (size_t)(c0 + r) * 16384 + n0 + q * 16;
#pragma unroll
  for (int i = 0; i < 4; i++) {
    float4 v = *(const float4*)(src + i * 4);
    tile[r][q * 16 + i * 4 + 0] = f2h(v.x);
    tile[r][q * 16 + i * 4 + 1] = f2h(v.y);
    tile[r][q * 16 + i * 4 + 2] = f2h(v.z);
    tile[r][q * 16 + i * 4 + 3] = f2h(v.w);
  }
  __syncthreads();
  int c = t & 63, pq = t >> 6;
  unsigned short* dst = xT + (size_t)b * 4194304 + (size_t)n0 * 256 + c0 + c;
#pragma unroll
  for (int i = 0; i < 16; i++) {
    int px = i * 4 + pq;
    dst[(size_t)px * 256] = tile[c][px];
  }
}

// ---------------- Q/V projection: x staged once, Wqvn from L2 -----------------
// Block = (64 px, batch). v output goes through Ls (LDS transpose) so global
// stores are full-128B-row coalesced (direct per-lane stores were 16x amplified).
__global__ __launch_bounds__(256) void proj(const unsigned short* __restrict__ xT,
                                            const unsigned short* __restrict__ Wqvn,
                                            const float* __restrict__ bq,
                                            const float* __restrict__ bv,
                                            unsigned short* __restrict__ qout,
                                            unsigned short* __restrict__ vT) {
  __shared__ __align__(16) unsigned short Xs[2048 * 8];   // 32 KB
  __shared__ __align__(16) unsigned short Ls[64 * 264];   // 33.8 KB v-transpose tile
  int n0 = blockIdx.x * 64, b = blockIdx.y;
  int tid = threadIdx.x, lane = tid & 63, w = tid >> 6;
  int l31 = lane & 31, hi = lane >> 5;
  const unsigned short* xb = xT + (size_t)b * 4194304;
  // stage x-tile: 2048 granules of 16B, source channel-granule pre-swizzled
#pragma unroll
  for (int it = 0; it < 8; it++) {
    int base = it * 256 + w * 64;
    int p = base + lane;
    int px = p >> 5, g = p & 31;
    int gs = g ^ (px & 31);
    const unsigned short* gsrc = xb + (size_t)(n0 + px) * 256 + gs * 8;
    __builtin_amdgcn_global_load_lds(
        (const __attribute__((address_space(1))) void*)gsrc,
        (__attribute__((address_space(3))) void*)&Xs[(size_t)base * 8], 16, 0, 0);
  }
  __syncthreads();

  f32x16 acc[4][2];
#pragma unroll
  for (int i = 0; i < 4; i++)
#pragma unroll
    for (int j = 0; j < 2; j++)
#pragma unroll
      for (int r = 0; r < 16; r++) acc[i][j][r] = 0.f;

#pragma unroll
  for (int ks = 0; ks < 16; ks++) {
    f16x8 bfr[2];
#pragma unroll
    for (int nt = 0; nt < 2; nt++) {
      int px = nt * 32 + l31;
      int gl = (ks * 2 + hi) ^ (px & 31);
      bfr[nt] = *(const f16x8*)&Xs[(px * 32 + gl) * 8];
    }
#pragma unroll
    for (int mj = 0; mj < 4; mj++) {
      int mt = w * 4 + mj;
      f16x8 afr = *(const f16x8*)(Wqvn + (size_t)(((mt * 16 + ks) * 2 + hi) * 32 + l31) * 8);
      acc[mj][0] = mfma32(afr, bfr[0], acc[mj][0]);
      acc[mj][1] = mfma32(afr, bfr[1], acc[mj][1]);
    }
  }

  if (w < 2) {  // q path: og = mt*32 + row
#pragma unroll
    for (int mj = 0; mj < 4; mj++) {
      int mt = w * 4 + mj;
#pragma unroll
      for (int nt = 0; nt < 2; nt++) {
        int n = n0 + nt * 32 + l31;
#pragma unroll
        for (int r = 0; r < 16; r++) {
          int og = mt * 32 + (r & 3) + 8 * (r >> 2) + 4 * hi;
          int h = og >> 6, o = og & 63;
          qout[((size_t)(h * 8 + b) * 64 + o) * 16384 + n] = f2h(acc[mj][nt][r] + bq[og]);
        }
      }
    }
  } else {  // v path: write into Ls[px][pg] (pg = global p 0..255)
#pragma unroll
    for (int mj = 0; mj < 4; mj++) {
      int mt = w * 4 + mj;
#pragma unroll
      for (int nt = 0; nt < 2; nt++) {
        int px = nt * 32 + l31;
#pragma unroll
        for (int rq = 0; rq < 4; rq++) {
          int pgb = (mt - 8) * 32 + 8 * rq + 4 * hi;
          unsigned short t0 = f2h(acc[mj][nt][rq * 4 + 0] + bv[pgb + 0]);
          unsigned short t1 = f2h(acc[mj][nt][rq * 4 + 1] + bv[pgb + 1]);
          unsigned short t2 = f2h(acc[mj][nt][rq * 4 + 2] + bv[pgb + 2]);
          unsigned short t3 = f2h(acc[mj][nt][rq * 4 + 3] + bv[pgb + 3]);
          uint2 pk;
          pk.x = (unsigned)t0 | ((unsigned)t1 << 16);
          pk.y = (unsigned)t2 | ((unsigned)t3 << 16);
          *(uint2*)&Ls[px * 264 + pgb] = pk;
        }
      }
    }
  }
  __syncthreads();
  // cooperative coalesced v-store: item (px 64) x (gq 32 granules of 8 p)
#pragma unroll
  for (int i = 0; i < 8; i++) {
    int item = i * 256 + tid;
    int px = item >> 5, gq = item & 31;
    int head = gq >> 3;
    uint4 v4 = *(const uint4*)&Ls[px * 264 + gq * 8];
    *(uint4*)&vT[((size_t)(head * 8 + b) * 16384 + n0 + px) * 64 + (gq & 7) * 8] = v4;
  }
}

// ---------------- dilated 3x3 conv (keys): 4 d-spaced rows, split-buffer pipe --
// (R10 config -- best measured.) Hs[2] halo double-buffer staged 2 ahead,
// counted vmcnt(7); Ws weights single-buffer staged 1 ahead.
__global__ __launch_bounds__(256, 2) void convk(const unsigned short* __restrict__ xT,
                                                const unsigned short* __restrict__ Wkb,
                                                const float* __restrict__ bk,
                                                const unsigned short* __restrict__ zp,
                                                unsigned short* __restrict__ kout) {
  __shared__ __align__(16) unsigned short Hs[2][1792 * 8];  // 2 x 28672 B
  __shared__ __align__(16) unsigned short Ws[1280 * 8];     // 20480 B
  // bijective XCD swizzle: 1024 blocks
  int orig = (blockIdx.x & 7) * 128 + (blockIdx.x >> 3);
  int g = orig & 31, b = (orig >> 5) & 7, h = orig >> 8;
  int d = 1 << h;
  int gpd = 32 >> h;
  int s = g / gpd;
  int q0 = (g - s * gpd) * 4;   // rows y = s + (q0+r)*d, r=0..3
  int nq = 128 >> h;
  int tid = threadIdx.x, lane = tid & 63, w = tid >> 6;  // w = col-quarter
  int l31 = lane & 31, hi = lane >> 5;
  const unsigned short* xb = xT + (size_t)b * 4194304;

  f32x16 acc[2][4];
#pragma unroll
  for (int i = 0; i < 2; i++)
#pragma unroll
    for (int j = 0; j < 4; j++)
#pragma unroll
      for (int r = 0; r < 16; r++) acc[i][j][r] = 0.f;

  // ---- halo pointers: items (slot*6+plane)*144+px, 7 loads/thread, stride 32B
  const char* hptr[7];
  int hstr[7];
#pragma unroll
  for (int it = 0; it < 7; it++) {
    int p = it * 256 + tid;
    hptr[it] = (const char*)zp;
    hstr[it] = 0;
    if (p < 1728) {
      int px = p % 144;
      int sp = p / 144;
      int plane = sp % 6, slot = sp / 6;
      int q = q0 + plane - 1;
      int xc = px - d;
      bool ok = (q >= 0) & (q < nq) & (xc >= 0) & (xc < 128);
      if (ok) {
        hptr[it] = (const char*)(xb + (size_t)((s + q * d) * 128 + xc) * 256 + slot * 8);
        hstr[it] = 32;
      }
    }
  }
  // ---- weight pointers: items (t*2+slot)*64+pp, 5 loads/thread, stride 2048B
  const char* wptr[5];
  int wstr[5];
#pragma unroll
  for (int it = 0; it < 5; it++) {
    int p = it * 256 + tid;
    wptr[it] = (const char*)zp;
    wstr[it] = 0;
    if (p < 1152) {
      int pp = p & 63, ts = p >> 6;
      int t = ts >> 1, slot = ts & 1;
      wptr[it] = (const char*)(Wkb + (size_t)(((h * 9 + t) * 32 + slot) * 64 + pp) * 8);
      wstr[it] = 2048;
    }
  }

  auto HSTAGE = [&](int bufi) {
#pragma unroll
    for (int it = 0; it < 7; it++) {
      int base = it * 256 + w * 64;
      __builtin_amdgcn_global_load_lds(
          (const __attribute__((address_space(1))) void*)hptr[it],
          (__attribute__((address_space(3))) void*)&Hs[bufi][(size_t)base * 8], 16, 0, 0);
      hptr[it] += hstr[it];
    }
  };
  auto WSTAGE = [&]() {
#pragma unroll
    for (int it = 0; it < 5; it++) {
      int base = it * 256 + w * 64;
      __builtin_amdgcn_global_load_lds(
          (const __attribute__((address_space(1))) void*)wptr[it],
          (__attribute__((address_space(3))) void*)&Ws[(size_t)base * 8], 16, 0, 0);
      wptr[it] += wstr[it];
    }
  };

  HSTAGE(0);   // halo 0
  WSTAGE();    // weights 0
  HSTAGE(1);   // halo 1
#pragma unroll 1
  for (int c = 0; c < 16; c++) {
    // need halo_c + w_c done; keep halo_{c+1} (7 loads) in flight
    if (c < 15) asm volatile("s_waitcnt vmcnt(7)" ::: "memory");
    else        asm volatile("s_waitcnt vmcnt(0)" ::: "memory");
    __builtin_amdgcn_s_barrier();
    __builtin_amdgcn_sched_barrier(0);
    int bufi = c & 1;
    __builtin_amdgcn_s_setprio(1);
#pragma unroll
    for (int tx = 0; tx < 3; tx++) {
      f16x8 bfr[6];
#pragma unroll
      for (int p6 = 0; p6 < 6; p6++)
        bfr[p6] = *(const f16x8*)&Hs[bufi][((hi * 6 + p6) * 144 + w * 32 + d * tx + l31) * 8];
#pragma unroll
      for (int ty = 0; ty < 3; ty++) {
        int t = ty * 3 + tx;
        f16x8 a0 = *(const f16x8*)&Ws[((t * 2 + hi) * 64 + l31) * 8];
        f16x8 a1 = *(const f16x8*)&Ws[((t * 2 + hi) * 64 + 32 + l31) * 8];
#pragma unroll
        for (int r = 0; r < 4; r++) {
          acc[0][r] = mfma32(a0, bfr[r + ty], acc[0][r]);
          acc[1][r] = mfma32(a1, bfr[r + ty], acc[1][r]);
        }
      }
    }
    __builtin_amdgcn_s_setprio(0);
    asm volatile("s_waitcnt lgkmcnt(0)" ::: "memory");
    __builtin_amdgcn_sched_barrier(0);
    __builtin_amdgcn_s_barrier();
    __builtin_amdgcn_sched_barrier(0);
    if (c < 15) WSTAGE();        // weights c+1 into Ws (now free)
    if (c < 14) HSTAGE(bufi);    // halo c+2 into Hs[bufi] (now free)
    __builtin_amdgcn_sched_barrier(0);
  }

  // epilogue: wave w owns cols w*32..w*32+31, rows r=0..3 (y = s+(q0+r)*d)
  unsigned short* kb = kout + (size_t)((h * 8 + b) * 64) * 16384;
#pragma unroll
  for (int mo = 0; mo < 2; mo++)
#pragma unroll
    for (int r = 0; r < 4; r++) {
      int y = s + (q0 + r) * d;
#pragma unroll
      for (int reg = 0; reg < 16; reg++) {
        int p = mo * 32 + (reg & 3) + 8 * (reg >> 2) + 4 * hi;
        int x = w * 32 + l31;
        kb[(size_t)p * 16384 + y * 128 + x] = f2h(acc[mo][r][reg] + bk[h * 64 + p]);
      }
    }
}

// ---------------- scores partials: q . k^T over n-chunk of 2048 ----------------
__global__ __launch_bounds__(256) void scoresk(const unsigned short* __restrict__ qin,
                                               const unsigned short* __restrict__ kin,
                                               float* __restrict__ part) {
  __shared__ __align__(16) unsigned short As[64 * 64];
  __shared__ __align__(16) unsigned short Bs[64 * 64];
  int nch = blockIdx.x, b = blockIdx.y, h = blockIdx.z;
  int tid = threadIdx.x, lane = tid & 63, w = tid >> 6;
  int l15 = lane & 15, uq = lane >> 4;
  const unsigned short* qb = qin + (size_t)((h * 8 + b) * 64) * 16384;
  const unsigned short* kb = kin + (size_t)((h * 8 + b) * 64) * 16384;
  int moff = (w >> 1) * 32, noff = (w & 1) * 32;
  const f32x4 fz = {0.f, 0.f, 0.f, 0.f};
  f32x4 acc[2][2] = {{fz, fz}, {fz, fz}};
  for (int ci = 0; ci < 32; ci++) {
    int nb = nch * 2048 + ci * 64;
    __syncthreads();
    for (int p = tid; p < 512; p += 256) {
      int row = p >> 3, j = p & 7;
      *(uint4*)&As[sw(row, j * 8)] = *(const uint4*)(qb + (size_t)row * 16384 + nb + j * 8);
      *(uint4*)&Bs[sw(row, j * 8)] = *(const uint4*)(kb + (size_t)row * 16384 + nb + j * 8);
    }
    __syncthreads();
#pragma unroll
    for (int kk = 0; kk < 2; kk++) {
      f16x8 b0 = *(const f16x8*)&Bs[sw(noff + l15, kk * 32 + uq * 8)];
      f16x8 b1 = *(const f16x8*)&Bs[sw(noff + 16 + l15, kk * 32 + uq * 8)];
      f16x8 a0 = *(const f16x8*)&As[sw(moff + l15, kk * 32 + uq * 8)];
      f16x8 a1 = *(const f16x8*)&As[sw(moff + 16 + l15, kk * 32 + uq * 8)];
      acc[0][0] = mfma16(a0, b0, acc[0][0]);
      acc[0][1] = mfma16(a0, b1, acc[0][1]);
      acc[1][0] = mfma16(a1, b0, acc[1][0]);
      acc[1][1] = mfma16(a1, b1, acc[1][1]);
    }
  }
  float* pb = part + (size_t)((nch * 4 + h) * 8 + b) * 4096;
#pragma unroll
  for (int mf = 0; mf < 2; mf++)
#pragma unroll
    for (int nf = 0; nf < 2; nf++) {
      int p = noff + nf * 16 + l15;
#pragma unroll
      for (int r = 0; r < 4; r++) {
        int o = moff + mf * 16 + 4 * uq + r;
        pb[o * 64 + p] = acc[mf][nf][r];
      }
    }
}

// ---------------- softmax over p (one wave per (h,b,o) row) ----------------
__global__ __launch_bounds__(256) void smax(const float* __restrict__ part,
                                            unsigned short* __restrict__ attn) {
  int row = blockIdx.x * 4 + (threadIdx.x >> 6);
  int lane = threadIdx.x & 63;
  int h = row >> 9, b = (row >> 6) & 7, o = row & 63;
  float s = 0.f;
#pragma unroll
  for (int nch = 0; nch < 8; nch++)
    s += part[(size_t)((nch * 4 + h) * 8 + b) * 4096 + o * 64 + lane];
  s *= 0.0625f;  // 1/sqrt(256)
  float m = s;
#pragma unroll
  for (int k = 32; k > 0; k >>= 1) m = fmaxf(m, __shfl_xor(m, k, 64));
  float e = __expf(s - m);
  float sum = e;
#pragma unroll
  for (int k = 32; k > 0; k >>= 1) sum += __shfl_xor(sum, k, 64);
  attn[(size_t)(h * 8 + b) * 4096 + o * 64 + lane] = f2h(e / sum);
}

// ---------------- out = attn @ v (staging via global_load_lds) ----------------
__global__ __launch_bounds__(256) void outk(const unsigned short* __restrict__ attn,
                                            const unsigned short* __restrict__ vT,
                                            float* __restrict__ out) {
  __shared__ __align__(16) unsigned short As[64 * 64];
  __shared__ __align__(16) unsigned short Bs[256 * 64];
  int n0 = blockIdx.x * 256, b = blockIdx.y, h = blockIdx.z;
  int tid = threadIdx.x, lane = tid & 63, w = tid >> 6;
  int l15 = lane & 15, uq = lane >> 4;
  const unsigned short* ab = attn + (size_t)(h * 8 + b) * 4096;
  const unsigned short* vb = vT + (size_t)(h * 8 + b) * 16384 * 64;
  // As: 512 granules; source granule pre-swizzled to match sw() reads
#pragma unroll
  for (int it = 0; it < 2; it++) {
    int base = it * 256 + w * 64;
    int p = base + lane;
    int row = p >> 3, j = p & 7;
    int gs = j ^ (row & 7);
    const unsigned short* gsrc = ab + row * 64 + gs * 8;
    __builtin_amdgcn_global_load_lds(
        (const __attribute__((address_space(1))) void*)gsrc,
        (__attribute__((address_space(3))) void*)&As[(size_t)base * 8], 16, 0, 0);
  }
  // Bs: 2048 granules
#pragma unroll
  for (int it = 0; it < 8; it++) {
    int base = it * 256 + w * 64;
    int p = base + lane;
    int px = p >> 3, j = p & 7;
    int gs = j ^ (px & 7);
    const unsigned short* gsrc = vb + (size_t)(n0 + px) * 64 + gs * 8;
    __builtin_amdgcn_global_load_lds(
        (const __attribute__((address_space(1))) void*)gsrc,
        (__attribute__((address_space(3))) void*)&Bs[(size_t)base * 8], 16, 0, 0);
  }
  __syncthreads();
  const f32x4 fz = {0.f, 0.f, 0.f, 0.f};
  f32x4 acc[4][4];
#pragma unroll
  for (int i = 0; i < 4; i++)
#pragma unroll
    for (int j = 0; j < 4; j++) acc[i][j] = fz;
#pragma unroll
  for (int kk = 0; kk < 2; kk++) {
    f16x8 bfr[4];
#pragma unroll
    for (int nf = 0; nf < 4; nf++)
      bfr[nf] = *(const f16x8*)&Bs[sw(w * 64 + nf * 16 + l15, kk * 32 + uq * 8)];
#pragma unroll
    for (int mf = 0; mf < 4; mf++) {
      f16x8 afr = *(const f16x8*)&As[sw(mf * 16 + l15, kk * 32 + uq * 8)];
#pragma unroll
      for (int nf = 0; nf < 4; nf++) acc[mf][nf] = mfma16(afr, bfr[nf], acc[mf][nf]);
    }
  }
  float* ob = out + (size_t)b * 4194304 + (size_t)(h * 64) * 16384;
#pragma unroll
  for (int mf = 0; mf < 4; mf++)
#pragma unroll
    for (int nf = 0; nf < 4; nf++) {
      int n = n0 + w * 64 + nf * 16 + l15;
#pragma unroll
      for (int r = 0; r < 4; r++) {
        int o = mf * 16 + 4 * uq + r;
        ob[(size_t)o * 16384 + n] = acc[mf][nf][r];
      }
    }
}

extern "C" void kernel_launch(void* const* d_in, const int* in_sizes, int n_in,
                              void* d_out, int out_size, void* d_ws, size_t ws_size,
                              hipStream_t stream) {
  const float* x  = (const float*)d_in[0];
  const float* Wq = (const float*)d_in[1];
  const float* bq = (const float*)d_in[2];
  const float* Wk = (const float*)d_in[3];
  const float* bk = (const float*)d_in[4];
  const float* Wv = (const float*)d_in[5];
  const float* bv = (const float*)d_in[6];
  float* out = (float*)d_out;

  char* ws = (char*)d_ws;
  unsigned short* kbuf = (unsigned short*)(ws);
  unsigned short* vT   = (unsigned short*)(ws + 67108864);
  unsigned short* attn = (unsigned short*)(ws + 134217728);
  unsigned short* Wqvn = (unsigned short*)(ws + 134479872);
  unsigned short* Wkb  = (unsigned short*)(ws + 134742016);
  unsigned short* zp   = (unsigned short*)(ws + 135921664);
  // d_out doubles as scratch: xT in first half, q in second; part reuses dead xT.
  unsigned short* xT = (unsigned short*)d_out;
  unsigned short* qb = (unsigned short*)d_out + 33554432;
  float* part = (float*)d_out;

  prep<<<dim3(2816), dim3(256), 0, stream>>>(Wq, Wv, Wk, Wqvn, Wkb, zp);
  xpose<<<dim3(256, 4, 8), dim3(256), 0, stream>>>(x, xT);
  proj<<<dim3(256, 8), dim3(256), 0, stream>>>(xT, Wqvn, bq, bv, qb, vT);
  convk<<<dim3(1024), dim3(256), 0, stream>>>(xT, Wkb, bk, zp, kbuf);
  scoresk<<<dim3(8, 8, 4), dim3(256), 0, stream>>>(qb, kbuf, part);
  smax<<<dim3(512), dim3(256), 0, stream>>>(part, attn);
  outk<<<dim3(64, 8, 4), dim3(256), 0, stream>>>(attn, vT, out);
}

// Round 14
// 382.056 us; speedup vs baseline: 1.1364x; 1.0629x over previous
//
#include <hip/hip_runtime.h>
#include <hip/hip_bf16.h>

// Channel attention (4 heads, dilated 3x3 key convs d=1,2,4,8), f16 MFMA pipeline.
// R14: fix R13's scoresk staging coverage (was loading 256/512 granules per tile
// -> rows 32-63 stale). 4 global_load_lds per thread, wave-uniform bases.
// xpose vectorized writes kept. convk/proj/outk unchanged (R12 = best measured).
//
// ws layout (bytes):
//   kbuf : [0,           67108864)   k  f16 [h][b][p][n]
//   vT   : [67108864,   134217728)   v  f16 [h][b][n][p]   (pixel-major)
//   attn : [134217728,  134479872)   attn f16 [h][b][o][p]
//   Wqvn : [134479872,  134742016)   f16 A-frag-native [mt16][ks16][hi2][m32][8]
//   Wkb  : [134742016,  135921664)   f16 [h][t][ks32][p64][8]  (MFMA A-frag native)
//   zpage: [135921664,  135922176)   zeros (OOB load source, 512 B)
// d_out reused as scratch (dead before final kernel):
//   xT   : bytes [0, 64Mi)   f16 [b][n][c]
//   q    : bytes [64Mi,128Mi) f16 [h][b][o][n]
//   part : bytes [0, 16Mi)   fp32 partial scores, 32 chunks (written AFTER conv)

typedef __attribute__((ext_vector_type(8))) _Float16 f16x8;
typedef __attribute__((ext_vector_type(4))) float f32x4;
typedef __attribute__((ext_vector_type(16))) float f32x16;

__device__ __forceinline__ unsigned short f2h(float f) {
  union { _Float16 h; unsigned short u; } v;
  v.h = (_Float16)f;
  return v.u;
}

__device__ __forceinline__ f32x4 mfma16(f16x8 a, f16x8 b, f32x4 c) {
  return __builtin_amdgcn_mfma_f32_16x16x32_f16(a, b, c, 0, 0, 0);
}
__device__ __forceinline__ f32x16 mfma32(f16x8 a, f16x8 b, f32x16 c) {
  return __builtin_amdgcn_mfma_f32_32x32x16_f16(a, b, c, 0, 0, 0);
}

// swizzled index into a [R][64]-ushort tile (128B rows): XOR bits 4..6 of byte off
__device__ __forceinline__ int sw(int row, int c) {
  return row * 64 + ((((c << 1) ^ ((row & 7) << 4)) >> 1));
}

// ---------------- weight prep ----------------
__global__ __launch_bounds__(256) void prep(const float* __restrict__ Wq,
                                            const float* __restrict__ Wv,
                                            const float* __restrict__ Wk,
                                            unsigned short* __restrict__ Wqvn,
                                            unsigned short* __restrict__ Wkb,
                                            unsigned short* __restrict__ zp) {
  int i = blockIdx.x * 256 + threadIdx.x;
  if (blockIdx.x == 0) zp[threadIdx.x] = 0;  // 512 B zero page
  const int total = 131072 + 589824;
  if (i >= total) return;
  if (i < 131072) {
    // Wqvn[(((mt*16+ks)*2+hi)*32 + m31)*8 + jj] = W[row=mt*32+m31][ch=ks*16+hi*8+jj]
    int jj = i & 7;
    int m31 = (i >> 3) & 31;
    int hi = (i >> 8) & 1;
    int ks = (i >> 9) & 15;
    int mt = i >> 13;
    int row = mt * 32 + m31;
    int ch = ks * 16 + hi * 8 + jj;
    Wqvn[i] = f2h(row < 256 ? Wq[row * 256 + ch] : Wv[(row - 256) * 256 + ch]);
  } else {
    int j = i - 131072;  // (((h*9+t)*32 + ks)*64 + p)*8 + jj
    int jj = j & 7;
    int p = (j >> 3) & 63;
    int ks = (j >> 9) & 31;
    int ht = j >> 14;
    int t = ht % 9;
    int h = ht / 9;
    Wkb[j] = f2h(Wk[(size_t)((h * 64 + p) * 256 + ks * 8 + jj) * 9 + t]);
  }
}

// ---------------- x (b,c,n) fp32 -> xT (b,n,c) f16 (vectorized stores) --------
__global__ __launch_bounds__(256) void xpose(const float* __restrict__ x,
                                             unsigned short* __restrict__ xT) {
  __shared__ unsigned short tile[64][66];
  int n0 = blockIdx.x * 64, c0 = blockIdx.y * 64, b = blockIdx.z;
  int t = threadIdx.x;
  int r = t >> 2, q = t & 3;
  const float* src = x + (size_t)b * 4194304 + (size_t)(c0 + r) * 16384 + n0 + q * 16;
#pragma unroll
  for (int i = 0; i < 4; i++) {
    float4 v = *(const float4*)(src + i * 4);
    tile[r][q * 16 + i * 4 + 0] = f2h(v.x);
    tile[r][q * 16 + i * 4 + 1] = f2h(v.y);
    tile[r][q * 16 + i * 4 + 2] = f2h(v.z);
    tile[r][q * 16 + i * 4 + 3] = f2h(v.w);
  }
  __syncthreads();
  // write: 8 channels per lane -> uint4; wave covers 8 px x 128B = 1KB/instr
  int c8 = (t & 7) * 8;
#pragma unroll
  for (int i = 0; i < 2; i++) {
    int px = i * 32 + (t >> 3);
    unsigned short v[8];
#pragma unroll
    for (int j = 0; j < 8; j++) v[j] = tile[c8 + j][px];
    *(uint4*)&xT[(size_t)b * 4194304 + (size_t)(n0 + px) * 256 + c0 + c8] =
        *(const uint4*)v;
  }
}

// ---------------- Q/V projection: x staged once, Wqvn from L2 -----------------
__global__ __launch_bounds__(256) void proj(const unsigned short* __restrict__ xT,
                                            const unsigned short* __restrict__ Wqvn,
                                            const float* __restrict__ bq,
                                            const float* __restrict__ bv,
                                            unsigned short* __restrict__ qout,
                                            unsigned short* __restrict__ vT) {
  __shared__ __align__(16) unsigned short Xs[2048 * 8];   // 32 KB
  __shared__ __align__(16) unsigned short Ls[64 * 264];   // 33.8 KB v-transpose tile
  int n0 = blockIdx.x * 64, b = blockIdx.y;
  int tid = threadIdx.x, lane = tid & 63, w = tid >> 6;
  int l31 = lane & 31, hi = lane >> 5;
  const unsigned short* xb = xT + (size_t)b * 4194304;
#pragma unroll
  for (int it = 0; it < 8; it++) {
    int base = it * 256 + w * 64;
    int p = base + lane;
    int px = p >> 5, g = p & 31;
    int gs = g ^ (px & 31);
    const unsigned short* gsrc = xb + (size_t)(n0 + px) * 256 + gs * 8;
    __builtin_amdgcn_global_load_lds(
        (const __attribute__((address_space(1))) void*)gsrc,
        (__attribute__((address_space(3))) void*)&Xs[(size_t)base * 8], 16, 0, 0);
  }
  __syncthreads();

  f32x16 acc[4][2];
#pragma unroll
  for (int i = 0; i < 4; i++)
#pragma unroll
    for (int j = 0; j < 2; j++)
#pragma unroll
      for (int r = 0; r < 16; r++) acc[i][j][r] = 0.f;

#pragma unroll
  for (int ks = 0; ks < 16; ks++) {
    f16x8 bfr[2];
#pragma unroll
    for (int nt = 0; nt < 2; nt++) {
      int px = nt * 32 + l31;
      int gl = (ks * 2 + hi) ^ (px & 31);
      bfr[nt] = *(const f16x8*)&Xs[(px * 32 + gl) * 8];
    }
#pragma unroll
    for (int mj = 0; mj < 4; mj++) {
      int mt = w * 4 + mj;
      f16x8 afr = *(const f16x8*)(Wqvn + (size_t)(((mt * 16 + ks) * 2 + hi) * 32 + l31) * 8);
      acc[mj][0] = mfma32(afr, bfr[0], acc[mj][0]);
      acc[mj][1] = mfma32(afr, bfr[1], acc[mj][1]);
    }
  }

  if (w < 2) {  // q path
#pragma unroll
    for (int mj = 0; mj < 4; mj++) {
      int mt = w * 4 + mj;
#pragma unroll
      for (int nt = 0; nt < 2; nt++) {
        int n = n0 + nt * 32 + l31;
#pragma unroll
        for (int r = 0; r < 16; r++) {
          int og = mt * 32 + (r & 3) + 8 * (r >> 2) + 4 * hi;
          int h = og >> 6, o = og & 63;
          qout[((size_t)(h * 8 + b) * 64 + o) * 16384 + n] = f2h(acc[mj][nt][r] + bq[og]);
        }
      }
    }
  } else {  // v path via LDS transpose
#pragma unroll
    for (int mj = 0; mj < 4; mj++) {
      int mt = w * 4 + mj;
#pragma unroll
      for (int nt = 0; nt < 2; nt++) {
        int px = nt * 32 + l31;
#pragma unroll
        for (int rq = 0; rq < 4; rq++) {
          int pgb = (mt - 8) * 32 + 8 * rq + 4 * hi;
          unsigned short t0 = f2h(acc[mj][nt][rq * 4 + 0] + bv[pgb + 0]);
          unsigned short t1 = f2h(acc[mj][nt][rq * 4 + 1] + bv[pgb + 1]);
          unsigned short t2 = f2h(acc[mj][nt][rq * 4 + 2] + bv[pgb + 2]);
          unsigned short t3 = f2h(acc[mj][nt][rq * 4 + 3] + bv[pgb + 3]);
          uint2 pk;
          pk.x = (unsigned)t0 | ((unsigned)t1 << 16);
          pk.y = (unsigned)t2 | ((unsigned)t3 << 16);
          *(uint2*)&Ls[px * 264 + pgb] = pk;
        }
      }
    }
  }
  __syncthreads();
#pragma unroll
  for (int i = 0; i < 8; i++) {
    int item = i * 256 + tid;
    int px = item >> 5, gq = item & 31;
    int head = gq >> 3;
    uint4 v4 = *(const uint4*)&Ls[px * 264 + gq * 8];
    *(uint4*)&vT[((size_t)(head * 8 + b) * 16384 + n0 + px) * 64 + (gq & 7) * 8] = v4;
  }
}

// ---------------- dilated 3x3 conv (keys): R10 config (best measured) ---------
__global__ __launch_bounds__(256, 2) void convk(const unsigned short* __restrict__ xT,
                                                const unsigned short* __restrict__ Wkb,
                                                const float* __restrict__ bk,
                                                const unsigned short* __restrict__ zp,
                                                unsigned short* __restrict__ kout) {
  __shared__ __align__(16) unsigned short Hs[2][1792 * 8];  // 2 x 28672 B
  __shared__ __align__(16) unsigned short Ws[1280 * 8];     // 20480 B
  int orig = (blockIdx.x & 7) * 128 + (blockIdx.x >> 3);
  int g = orig & 31, b = (orig >> 5) & 7, h = orig >> 8;
  int d = 1 << h;
  int gpd = 32 >> h;
  int s = g / gpd;
  int q0 = (g - s * gpd) * 4;
  int nq = 128 >> h;
  int tid = threadIdx.x, lane = tid & 63, w = tid >> 6;
  int l31 = lane & 31, hi = lane >> 5;
  const unsigned short* xb = xT + (size_t)b * 4194304;

  f32x16 acc[2][4];
#pragma unroll
  for (int i = 0; i < 2; i++)
#pragma unroll
    for (int j = 0; j < 4; j++)
#pragma unroll
      for (int r = 0; r < 16; r++) acc[i][j][r] = 0.f;

  const char* hptr[7];
  int hstr[7];
#pragma unroll
  for (int it = 0; it < 7; it++) {
    int p = it * 256 + tid;
    hptr[it] = (const char*)zp;
    hstr[it] = 0;
    if (p < 1728) {
      int px = p % 144;
      int sp = p / 144;
      int plane = sp % 6, slot = sp / 6;
      int q = q0 + plane - 1;
      int xc = px - d;
      bool ok = (q >= 0) & (q < nq) & (xc >= 0) & (xc < 128);
      if (ok) {
        hptr[it] = (const char*)(xb + (size_t)((s + q * d) * 128 + xc) * 256 + slot * 8);
        hstr[it] = 32;
      }
    }
  }
  const char* wptr[5];
  int wstr[5];
#pragma unroll
  for (int it = 0; it < 5; it++) {
    int p = it * 256 + tid;
    wptr[it] = (const char*)zp;
    wstr[it] = 0;
    if (p < 1152) {
      int pp = p & 63, ts = p >> 6;
      int t = ts >> 1, slot = ts & 1;
      wptr[it] = (const char*)(Wkb + (size_t)(((h * 9 + t) * 32 + slot) * 64 + pp) * 8);
      wstr[it] = 2048;
    }
  }

  auto HSTAGE = [&](int bufi) {
#pragma unroll
    for (int it = 0; it < 7; it++) {
      int base = it * 256 + w * 64;
      __builtin_amdgcn_global_load_lds(
          (const __attribute__((address_space(1))) void*)hptr[it],
          (__attribute__((address_space(3))) void*)&Hs[bufi][(size_t)base * 8], 16, 0, 0);
      hptr[it] += hstr[it];
    }
  };
  auto WSTAGE = [&]() {
#pragma unroll
    for (int it = 0; it < 5; it++) {
      int base = it * 256 + w * 64;
      __builtin_amdgcn_global_load_lds(
          (const __attribute__((address_space(1))) void*)wptr[it],
          (__attribute__((address_space(3))) void*)&Ws[(size_t)base * 8], 16, 0, 0);
      wptr[it] += wstr[it];
    }
  };

  HSTAGE(0);
  WSTAGE();
  HSTAGE(1);
#pragma unroll 1
  for (int c = 0; c < 16; c++) {
    if (c < 15) asm volatile("s_waitcnt vmcnt(7)" ::: "memory");
    else        asm volatile("s_waitcnt vmcnt(0)" ::: "memory");
    __builtin_amdgcn_s_barrier();
    __builtin_amdgcn_sched_barrier(0);
    int bufi = c & 1;
    __builtin_amdgcn_s_setprio(1);
#pragma unroll
    for (int tx = 0; tx < 3; tx++) {
      f16x8 bfr[6];
#pragma unroll
      for (int p6 = 0; p6 < 6; p6++)
        bfr[p6] = *(const f16x8*)&Hs[bufi][((hi * 6 + p6) * 144 + w * 32 + d * tx + l31) * 8];
#pragma unroll
      for (int ty = 0; ty < 3; ty++) {
        int t = ty * 3 + tx;
        f16x8 a0 = *(const f16x8*)&Ws[((t * 2 + hi) * 64 + l31) * 8];
        f16x8 a1 = *(const f16x8*)&Ws[((t * 2 + hi) * 64 + 32 + l31) * 8];
#pragma unroll
        for (int r = 0; r < 4; r++) {
          acc[0][r] = mfma32(a0, bfr[r + ty], acc[0][r]);
          acc[1][r] = mfma32(a1, bfr[r + ty], acc[1][r]);
        }
      }
    }
    __builtin_amdgcn_s_setprio(0);
    asm volatile("s_waitcnt lgkmcnt(0)" ::: "memory");
    __builtin_amdgcn_sched_barrier(0);
    __builtin_amdgcn_s_barrier();
    __builtin_amdgcn_sched_barrier(0);
    if (c < 15) WSTAGE();
    if (c < 14) HSTAGE(bufi);
    __builtin_amdgcn_sched_barrier(0);
  }

  unsigned short* kb = kout + (size_t)((h * 8 + b) * 64) * 16384;
#pragma unroll
  for (int mo = 0; mo < 2; mo++)
#pragma unroll
    for (int r = 0; r < 4; r++) {
      int y = s + (q0 + r) * d;
#pragma unroll
      for (int reg = 0; reg < 16; reg++) {
        int p = mo * 32 + (reg & 3) + 8 * (reg >> 2) + 4 * hi;
        int x = w * 32 + l31;
        kb[(size_t)p * 16384 + y * 128 + x] = f2h(acc[mo][r][reg] + bk[h * 64 + p]);
      }
    }
}

// ---------------- scores partials: 1024 blocks (4/CU), gload_lds staging ------
__global__ __launch_bounds__(256) void scoresk(const unsigned short* __restrict__ qin,
                                               const unsigned short* __restrict__ kin,
                                               float* __restrict__ part) {
  __shared__ __align__(16) unsigned short As[64 * 64];
  __shared__ __align__(16) unsigned short Bs[64 * 64];
  int nch = blockIdx.x, b = blockIdx.y, h = blockIdx.z;
  int tid = threadIdx.x, lane = tid & 63, w = tid >> 6;
  int l15 = lane & 15, uq = lane >> 4;
  const unsigned short* qb = qin + (size_t)((h * 8 + b) * 64) * 16384;
  const unsigned short* kb = kin + (size_t)((h * 8 + b) * 64) * 16384;
  int moff = (w >> 1) * 32, noff = (w & 1) * 32;
  const f32x4 fz = {0.f, 0.f, 0.f, 0.f};
  f32x4 acc[2][2] = {{fz, fz}, {fz, fz}};
  const unsigned short* srcb = (w < 2) ? qb : kb;
  unsigned short* dst = (w < 2) ? As : Bs;
  int pbase = (w & 1) * 64;  // wave-uniform
  for (int ci = 0; ci < 8; ci++) {
    int nb = nch * 512 + ci * 64;
    __syncthreads();
    // stage A (q) and B (k): 512 granules per tile; waves (0,1)->A, (2,3)->B;
    // each thread 4 loads at wave-uniform bases pbase + k*128 (full coverage).
#pragma unroll
    for (int k4 = 0; k4 < 4; k4++) {
      int p = pbase + k4 * 128 + lane;
      int row = p >> 3, j = p & 7;
      int gs = j ^ (row & 7);
      const unsigned short* gsrc = srcb + (size_t)row * 16384 + nb + gs * 8;
      __builtin_amdgcn_global_load_lds(
          (const __attribute__((address_space(1))) void*)gsrc,
          (__attribute__((address_space(3))) void*)&dst[(size_t)(pbase + k4 * 128) * 8],
          16, 0, 0);
    }
    asm volatile("s_waitcnt vmcnt(0)" ::: "memory");
    __syncthreads();
#pragma unroll
    for (int kk = 0; kk < 2; kk++) {
      f16x8 b0 = *(const f16x8*)&Bs[sw(noff + l15, kk * 32 + uq * 8)];
      f16x8 b1 = *(const f16x8*)&Bs[sw(noff + 16 + l15, kk * 32 + uq * 8)];
      f16x8 a0 = *(const f16x8*)&As[sw(moff + l15, kk * 32 + uq * 8)];
      f16x8 a1 = *(const f16x8*)&As[sw(moff + 16 + l15, kk * 32 + uq * 8)];
      acc[0][0] = mfma16(a0, b0, acc[0][0]);
      acc[0][1] = mfma16(a0, b1, acc[0][1]);
      acc[1][0] = mfma16(a1, b0, acc[1][0]);
      acc[1][1] = mfma16(a1, b1, acc[1][1]);
    }
  }
  float* pb = part + (size_t)((nch * 4 + h) * 8 + b) * 4096;
#pragma unroll
  for (int mf = 0; mf < 2; mf++)
#pragma unroll
    for (int nf = 0; nf < 2; nf++) {
      int p = noff + nf * 16 + l15;
#pragma unroll
      for (int r = 0; r < 4; r++) {
        int o = moff + mf * 16 + 4 * uq + r;
        pb[o * 64 + p] = acc[mf][nf][r];
      }
    }
}

// ---------------- softmax over p (one wave per (h,b,o) row) ----------------
__global__ __launch_bounds__(256) void smax(const float* __restrict__ part,
                                            unsigned short* __restrict__ attn) {
  int row = blockIdx.x * 4 + (threadIdx.x >> 6);
  int lane = threadIdx.x & 63;
  int h = row >> 9, b = (row >> 6) & 7, o = row & 63;
  float s = 0.f;
#pragma unroll
  for (int nch = 0; nch < 32; nch++)
    s += part[(size_t)((nch * 4 + h) * 8 + b) * 4096 + o * 64 + lane];
  s *= 0.0625f;  // 1/sqrt(256)
  float m = s;
#pragma unroll
  for (int k = 32; k > 0; k >>= 1) m = fmaxf(m, __shfl_xor(m, k, 64));
  float e = __expf(s - m);
  float sum = e;
#pragma unroll
  for (int k = 32; k > 0; k >>= 1) sum += __shfl_xor(sum, k, 64);
  attn[(size_t)(h * 8 + b) * 4096 + o * 64 + lane] = f2h(e / sum);
}

// ---------------- out = attn @ v (staging via global_load_lds) ----------------
__global__ __launch_bounds__(256) void outk(const unsigned short* __restrict__ attn,
                                            const unsigned short* __restrict__ vT,
                                            float* __restrict__ out) {
  __shared__ __align__(16) unsigned short As[64 * 64];
  __shared__ __align__(16) unsigned short Bs[256 * 64];
  int n0 = blockIdx.x * 256, b = blockIdx.y, h = blockIdx.z;
  int tid = threadIdx.x, lane = tid & 63, w = tid >> 6;
  int l15 = lane & 15, uq = lane >> 4;
  const unsigned short* ab = attn + (size_t)(h * 8 + b) * 4096;
  const unsigned short* vb = vT + (size_t)(h * 8 + b) * 16384 * 64;
#pragma unroll
  for (int it = 0; it < 2; it++) {
    int base = it * 256 + w * 64;
    int p = base + lane;
    int row = p >> 3, j = p & 7;
    int gs = j ^ (row & 7);
    const unsigned short* gsrc = ab + row * 64 + gs * 8;
    __builtin_amdgcn_global_load_lds(
        (const __attribute__((address_space(1))) void*)gsrc,
        (__attribute__((address_space(3))) void*)&As[(size_t)base * 8], 16, 0, 0);
  }
#pragma unroll
  for (int it = 0; it < 8; it++) {
    int base = it * 256 + w * 64;
    int p = base + lane;
    int px = p >> 3, j = p & 7;
    int gs = j ^ (px & 7);
    const unsigned short* gsrc = vb + (size_t)(n0 + px) * 64 + gs * 8;
    __builtin_amdgcn_global_load_lds(
        (const __attribute__((address_space(1))) void*)gsrc,
        (__attribute__((address_space(3))) void*)&Bs[(size_t)base * 8], 16, 0, 0);
  }
  __syncthreads();
  const f32x4 fz = {0.f, 0.f, 0.f, 0.f};
  f32x4 acc[4][4];
#pragma unroll
  for (int i = 0; i < 4; i++)
#pragma unroll
    for (int j = 0; j < 4; j++) acc[i][j] = fz;
#pragma unroll
  for (int kk = 0; kk < 2; kk++) {
    f16x8 bfr[4];
#pragma unroll
    for (int nf = 0; nf < 4; nf++)
      bfr[nf] = *(const f16x8*)&Bs[sw(w * 64 + nf * 16 + l15, kk * 32 + uq * 8)];
#pragma unroll
    for (int mf = 0; mf < 4; mf++) {
      f16x8 afr = *(const f16x8*)&As[sw(mf * 16 + l15, kk * 32 + uq * 8)];
#pragma unroll
      for (int nf = 0; nf < 4; nf++) acc[mf][nf] = mfma16(afr, bfr[nf], acc[mf][nf]);
    }
  }
  float* ob = out + (size_t)b * 4194304 + (size_t)(h * 64) * 16384;
#pragma unroll
  for (int mf = 0; mf < 4; mf++)
#pragma unroll
    for (int nf = 0; nf < 4; nf++) {
      int n = n0 + w * 64 + nf * 16 + l15;
#pragma unroll
      for (int r = 0; r < 4; r++) {
        int o = mf * 16 + 4 * uq + r;
        ob[(size_t)o * 16384 + n] = acc[mf][nf][r];
      }
    }
}

extern "C" void kernel_launch(void* const* d_in, const int* in_sizes, int n_in,
                              void* d_out, int out_size, void* d_ws, size_t ws_size,
                              hipStream_t stream) {
  const float* x  = (const float*)d_in[0];
  const float* Wq = (const float*)d_in[1];
  const float* bq = (const float*)d_in[2];
  const float* Wk = (const float*)d_in[3];
  const float* bk = (const float*)d_in[4];
  const float* Wv = (const float*)d_in[5];
  const float* bv = (const float*)d_in[6];
  float* out = (float*)d_out;

  char* ws = (char*)d_ws;
  unsigned short* kbuf = (unsigned short*)(ws);
  unsigned short* vT   = (unsigned short*)(ws + 67108864);
  unsigned short* attn = (unsigned short*)(ws + 134217728);
  unsigned short* Wqvn = (unsigned short*)(ws + 134479872);
  unsigned short* Wkb  = (unsigned short*)(ws + 134742016);
  unsigned short* zp   = (unsigned short*)(ws + 135921664);
  // d_out doubles as scratch: xT in first half, q in second; part reuses dead xT.
  unsigned short* xT = (unsigned short*)d_out;
  unsigned short* qb = (unsigned short*)d_out + 33554432;
  float* part = (float*)d_out;

  prep<<<dim3(2816), dim3(256), 0, stream>>>(Wq, Wv, Wk, Wqvn, Wkb, zp);
  xpose<<<dim3(256, 4, 8), dim3(256), 0, stream>>>(x, xT);
  proj<<<dim3(256, 8), dim3(256), 0, stream>>>(xT, Wqvn, bq, bv, qb, vT);
  convk<<<dim3(1024), dim3(256), 0, stream>>>(xT, Wkb, bk, zp, kbuf);
  scoresk<<<dim3(32, 8, 4), dim3(256), 0, stream>>>(qb, kbuf, part);
  smax<<<dim3(512), dim3(256), 0, stream>>>(part, attn);
  outk<<<dim3(64, 8, 4), dim3(256), 0, stream>>>(attn, vT, out);
}

// Round 15
// 350.915 us; speedup vs baseline: 1.2372x; 1.0887x over previous
//
#include <hip/hip_runtime.h>
#include <hip/hip_bf16.h>

// Channel attention (4 heads, dilated 3x3 key convs d=1,2,4,8), f16 MFMA pipeline.
// R15: channel-slab xT layout xT2[b][slab16][n][16ch] -- convk's per-chunk halo
// read becomes a dense contiguous plane (was 32B-of-512B strided slices thrashing
// L2, 2.4x over-fetch). xpose write / proj stage / convk stage re-addressed;
// all compute, LDS layouts, and schedules unchanged from R14.
//
// ws layout (bytes):
//   kbuf : [0,           67108864)   k  f16 [h][b][p][n]
//   vT   : [67108864,   134217728)   v  f16 [h][b][n][p]   (pixel-major)
//   attn : [134217728,  134479872)   attn f16 [h][b][o][p]
//   Wqvn : [134479872,  134742016)   f16 A-frag-native [mt16][ks16][hi2][m32][8]
//   Wkb  : [134742016,  135921664)   f16 [h][t][ks32][p64][8]  (MFMA A-frag native)
//   zpage: [135921664,  135922176)   zeros (OOB load source, 512 B)
// d_out reused as scratch (dead before final kernel):
//   xT2  : bytes [0, 64Mi)   f16 [b][slab16][n][16]
//   q    : bytes [64Mi,128Mi) f16 [h][b][o][n]
//   part : bytes [0, 16Mi)   fp32 partial scores, 32 chunks (written AFTER conv)

typedef __attribute__((ext_vector_type(8))) _Float16 f16x8;
typedef __attribute__((ext_vector_type(4))) float f32x4;
typedef __attribute__((ext_vector_type(16))) float f32x16;

__device__ __forceinline__ unsigned short f2h(float f) {
  union { _Float16 h; unsigned short u; } v;
  v.h = (_Float16)f;
  return v.u;
}

__device__ __forceinline__ f32x4 mfma16(f16x8 a, f16x8 b, f32x4 c) {
  return __builtin_amdgcn_mfma_f32_16x16x32_f16(a, b, c, 0, 0, 0);
}
__device__ __forceinline__ f32x16 mfma32(f16x8 a, f16x8 b, f32x16 c) {
  return __builtin_amdgcn_mfma_f32_32x32x16_f16(a, b, c, 0, 0, 0);
}

// swizzled index into a [R][64]-ushort tile (128B rows): XOR bits 4..6 of byte off
__device__ __forceinline__ int sw(int row, int c) {
  return row * 64 + ((((c << 1) ^ ((row & 7) << 4)) >> 1));
}

// ---------------- weight prep ----------------
__global__ __launch_bounds__(256) void prep(const float* __restrict__ Wq,
                                            const float* __restrict__ Wv,
                                            const float* __restrict__ Wk,
                                            unsigned short* __restrict__ Wqvn,
                                            unsigned short* __restrict__ Wkb,
                                            unsigned short* __restrict__ zp) {
  int i = blockIdx.x * 256 + threadIdx.x;
  if (blockIdx.x == 0) zp[threadIdx.x] = 0;  // 512 B zero page
  const int total = 131072 + 589824;
  if (i >= total) return;
  if (i < 131072) {
    int jj = i & 7;
    int m31 = (i >> 3) & 31;
    int hi = (i >> 8) & 1;
    int ks = (i >> 9) & 15;
    int mt = i >> 13;
    int row = mt * 32 + m31;
    int ch = ks * 16 + hi * 8 + jj;
    Wqvn[i] = f2h(row < 256 ? Wq[row * 256 + ch] : Wv[(row - 256) * 256 + ch]);
  } else {
    int j = i - 131072;  // (((h*9+t)*32 + ks)*64 + p)*8 + jj
    int jj = j & 7;
    int p = (j >> 3) & 63;
    int ks = (j >> 9) & 31;
    int ht = j >> 14;
    int t = ht % 9;
    int h = ht / 9;
    Wkb[j] = f2h(Wk[(size_t)((h * 64 + p) * 256 + ks * 8 + jj) * 9 + t]);
  }
}

// ---------------- x (b,c,n) fp32 -> xT2 [b][slab][n][16] f16 ------------------
__global__ __launch_bounds__(256) void xpose(const float* __restrict__ x,
                                             unsigned short* __restrict__ xT) {
  __shared__ unsigned short tile[64][66];
  int n0 = blockIdx.x * 64, c0 = blockIdx.y * 64, b = blockIdx.z;
  int t = threadIdx.x;
  int r = t >> 2, q = t & 3;
  const float* src = x + (size_t)b * 4194304 + (size_t)(c0 + r) * 16384 + n0 + q * 16;
#pragma unroll
  for (int i = 0; i < 4; i++) {
    float4 v = *(const float4*)(src + i * 4);
    tile[r][q * 16 + i * 4 + 0] = f2h(v.x);
    tile[r][q * 16 + i * 4 + 1] = f2h(v.y);
    tile[r][q * 16 + i * 4 + 2] = f2h(v.z);
    tile[r][q * 16 + i * 4 + 3] = f2h(v.w);
  }
  __syncthreads();
  // write: thread = (slab-local s4 = t>>6, px = t&63); 16 ch -> two uint4.
  // wave covers 64 consecutive px within one slab (32B stride, 16B per store).
  int px = t & 63, s4 = t >> 6;
  unsigned short v[16];
#pragma unroll
  for (int j = 0; j < 16; j++) v[j] = tile[s4 * 16 + j][px];
  unsigned short* dst = xT + (size_t)b * 4194304 + (size_t)((c0 >> 4) + s4) * 262144 +
                        (size_t)(n0 + px) * 16;
  *(uint4*)&dst[0] = *(const uint4*)&v[0];
  *(uint4*)&dst[8] = *(const uint4*)&v[8];
}

// ---------------- Q/V projection: x staged once, Wqvn from L2 -----------------
__global__ __launch_bounds__(256) void proj(const unsigned short* __restrict__ xT,
                                            const unsigned short* __restrict__ Wqvn,
                                            const float* __restrict__ bq,
                                            const float* __restrict__ bv,
                                            unsigned short* __restrict__ qout,
                                            unsigned short* __restrict__ vT) {
  __shared__ __align__(16) unsigned short Xs[2048 * 8];   // 32 KB
  __shared__ __align__(16) unsigned short Ls[64 * 264];   // 33.8 KB v-transpose tile
  int n0 = blockIdx.x * 64, b = blockIdx.y;
  int tid = threadIdx.x, lane = tid & 63, w = tid >> 6;
  int l31 = lane & 31, hi = lane >> 5;
  const unsigned short* xb = xT + (size_t)b * 4194304;
  // stage x-tile: granule (px, g); global granule gs = g^(px&31) lives in
  // slab gs>>1 at half gs&1 (slab layout).
#pragma unroll
  for (int it = 0; it < 8; it++) {
    int base = it * 256 + w * 64;
    int p = base + lane;
    int px = p >> 5, g = p & 31;
    int gs = g ^ (px & 31);
    const unsigned short* gsrc =
        xb + (size_t)(gs >> 1) * 262144 + (size_t)(n0 + px) * 16 + (gs & 1) * 8;
    __builtin_amdgcn_global_load_lds(
        (const __attribute__((address_space(1))) void*)gsrc,
        (__attribute__((address_space(3))) void*)&Xs[(size_t)base * 8], 16, 0, 0);
  }
  __syncthreads();

  f32x16 acc[4][2];
#pragma unroll
  for (int i = 0; i < 4; i++)
#pragma unroll
    for (int j = 0; j < 2; j++)
#pragma unroll
      for (int r = 0; r < 16; r++) acc[i][j][r] = 0.f;

#pragma unroll
  for (int ks = 0; ks < 16; ks++) {
    f16x8 bfr[2];
#pragma unroll
    for (int nt = 0; nt < 2; nt++) {
      int px = nt * 32 + l31;
      int gl = (ks * 2 + hi) ^ (px & 31);
      bfr[nt] = *(const f16x8*)&Xs[(px * 32 + gl) * 8];
    }
#pragma unroll
    for (int mj = 0; mj < 4; mj++) {
      int mt = w * 4 + mj;
      f16x8 afr = *(const f16x8*)(Wqvn + (size_t)(((mt * 16 + ks) * 2 + hi) * 32 + l31) * 8);
      acc[mj][0] = mfma32(afr, bfr[0], acc[mj][0]);
      acc[mj][1] = mfma32(afr, bfr[1], acc[mj][1]);
    }
  }

  if (w < 2) {  // q path
#pragma unroll
    for (int mj = 0; mj < 4; mj++) {
      int mt = w * 4 + mj;
#pragma unroll
      for (int nt = 0; nt < 2; nt++) {
        int n = n0 + nt * 32 + l31;
#pragma unroll
        for (int r = 0; r < 16; r++) {
          int og = mt * 32 + (r & 3) + 8 * (r >> 2) + 4 * hi;
          int h = og >> 6, o = og & 63;
          qout[((size_t)(h * 8 + b) * 64 + o) * 16384 + n] = f2h(acc[mj][nt][r] + bq[og]);
        }
      }
    }
  } else {  // v path via LDS transpose
#pragma unroll
    for (int mj = 0; mj < 4; mj++) {
      int mt = w * 4 + mj;
#pragma unroll
      for (int nt = 0; nt < 2; nt++) {
        int px = nt * 32 + l31;
#pragma unroll
        for (int rq = 0; rq < 4; rq++) {
          int pgb = (mt - 8) * 32 + 8 * rq + 4 * hi;
          unsigned short t0 = f2h(acc[mj][nt][rq * 4 + 0] + bv[pgb + 0]);
          unsigned short t1 = f2h(acc[mj][nt][rq * 4 + 1] + bv[pgb + 1]);
          unsigned short t2 = f2h(acc[mj][nt][rq * 4 + 2] + bv[pgb + 2]);
          unsigned short t3 = f2h(acc[mj][nt][rq * 4 + 3] + bv[pgb + 3]);
          uint2 pk;
          pk.x = (unsigned)t0 | ((unsigned)t1 << 16);
          pk.y = (unsigned)t2 | ((unsigned)t3 << 16);
          *(uint2*)&Ls[px * 264 + pgb] = pk;
        }
      }
    }
  }
  __syncthreads();
#pragma unroll
  for (int i = 0; i < 8; i++) {
    int item = i * 256 + tid;
    int px = item >> 5, gq = item & 31;
    int head = gq >> 3;
    uint4 v4 = *(const uint4*)&Ls[px * 264 + gq * 8];
    *(uint4*)&vT[((size_t)(head * 8 + b) * 16384 + n0 + px) * 64 + (gq & 7) * 8] = v4;
  }
}

// ---------------- dilated 3x3 conv (keys): R10 schedule + slab xT -------------
__global__ __launch_bounds__(256, 2) void convk(const unsigned short* __restrict__ xT,
                                                const unsigned short* __restrict__ Wkb,
                                                const float* __restrict__ bk,
                                                const unsigned short* __restrict__ zp,
                                                unsigned short* __restrict__ kout) {
  __shared__ __align__(16) unsigned short Hs[2][1792 * 8];  // 2 x 28672 B
  __shared__ __align__(16) unsigned short Ws[1280 * 8];     // 20480 B
  int orig = (blockIdx.x & 7) * 128 + (blockIdx.x >> 3);
  int g = orig & 31, b = (orig >> 5) & 7, h = orig >> 8;
  int d = 1 << h;
  int gpd = 32 >> h;
  int s = g / gpd;
  int q0 = (g - s * gpd) * 4;
  int nq = 128 >> h;
  int tid = threadIdx.x, lane = tid & 63, w = tid >> 6;
  int l31 = lane & 31, hi = lane >> 5;
  const unsigned short* xb = xT + (size_t)b * 4194304;

  f32x16 acc[2][4];
#pragma unroll
  for (int i = 0; i < 2; i++)
#pragma unroll
    for (int j = 0; j < 4; j++)
#pragma unroll
      for (int r = 0; r < 16; r++) acc[i][j][r] = 0.f;

  // halo items (slot*6+plane)*144+px; slab layout: pixel entry = 32B in slab c,
  // slot*8 = 16B half. Per-chunk stride = one slab = 524288 B.
  const char* hptr[7];
  int hstr[7];
#pragma unroll
  for (int it = 0; it < 7; it++) {
    int p = it * 256 + tid;
    hptr[it] = (const char*)zp;
    hstr[it] = 0;
    if (p < 1728) {
      int px = p % 144;
      int sp = p / 144;
      int plane = sp % 6, slot = sp / 6;
      int q = q0 + plane - 1;
      int xc = px - d;
      bool ok = (q >= 0) & (q < nq) & (xc >= 0) & (xc < 128);
      if (ok) {
        hptr[it] = (const char*)(xb + (size_t)((s + q * d) * 128 + xc) * 16 + slot * 8);
        hstr[it] = 524288;
      }
    }
  }
  const char* wptr[5];
  int wstr[5];
#pragma unroll
  for (int it = 0; it < 5; it++) {
    int p = it * 256 + tid;
    wptr[it] = (const char*)zp;
    wstr[it] = 0;
    if (p < 1152) {
      int pp = p & 63, ts = p >> 6;
      int t = ts >> 1, slot = ts & 1;
      wptr[it] = (const char*)(Wkb + (size_t)(((h * 9 + t) * 32 + slot) * 64 + pp) * 8);
      wstr[it] = 2048;
    }
  }

  auto HSTAGE = [&](int bufi) {
#pragma unroll
    for (int it = 0; it < 7; it++) {
      int base = it * 256 + w * 64;
      __builtin_amdgcn_global_load_lds(
          (const __attribute__((address_space(1))) void*)hptr[it],
          (__attribute__((address_space(3))) void*)&Hs[bufi][(size_t)base * 8], 16, 0, 0);
      hptr[it] += hstr[it];
    }
  };
  auto WSTAGE = [&]() {
#pragma unroll
    for (int it = 0; it < 5; it++) {
      int base = it * 256 + w * 64;
      __builtin_amdgcn_global_load_lds(
          (const __attribute__((address_space(1))) void*)wptr[it],
          (__attribute__((address_space(3))) void*)&Ws[(size_t)base * 8], 16, 0, 0);
      wptr[it] += wstr[it];
    }
  };

  HSTAGE(0);
  WSTAGE();
  HSTAGE(1);
#pragma unroll 1
  for (int c = 0; c < 16; c++) {
    if (c < 15) asm volatile("s_waitcnt vmcnt(7)" ::: "memory");
    else        asm volatile("s_waitcnt vmcnt(0)" ::: "memory");
    __builtin_amdgcn_s_barrier();
    __builtin_amdgcn_sched_barrier(0);
    int bufi = c & 1;
    __builtin_amdgcn_s_setprio(1);
#pragma unroll
    for (int tx = 0; tx < 3; tx++) {
      f16x8 bfr[6];
#pragma unroll
      for (int p6 = 0; p6 < 6; p6++)
        bfr[p6] = *(const f16x8*)&Hs[bufi][((hi * 6 + p6) * 144 + w * 32 + d * tx + l31) * 8];
#pragma unroll
      for (int ty = 0; ty < 3; ty++) {
        int t = ty * 3 + tx;
        f16x8 a0 = *(const f16x8*)&Ws[((t * 2 + hi) * 64 + l31) * 8];
        f16x8 a1 = *(const f16x8*)&Ws[((t * 2 + hi) * 64 + 32 + l31) * 8];
#pragma unroll
        for (int r = 0; r < 4; r++) {
          acc[0][r] = mfma32(a0, bfr[r + ty], acc[0][r]);
          acc[1][r] = mfma32(a1, bfr[r + ty], acc[1][r]);
        }
      }
    }
    __builtin_amdgcn_s_setprio(0);
    asm volatile("s_waitcnt lgkmcnt(0)" ::: "memory");
    __builtin_amdgcn_sched_barrier(0);
    __builtin_amdgcn_s_barrier();
    __builtin_amdgcn_sched_barrier(0);
    if (c < 15) WSTAGE();
    if (c < 14) HSTAGE(bufi);
    __builtin_amdgcn_sched_barrier(0);
  }

  unsigned short* kb = kout + (size_t)((h * 8 + b) * 64) * 16384;
#pragma unroll
  for (int mo = 0; mo < 2; mo++)
#pragma unroll
    for (int r = 0; r < 4; r++) {
      int y = s + (q0 + r) * d;
#pragma unroll
      for (int reg = 0; reg < 16; reg++) {
        int p = mo * 32 + (reg & 3) + 8 * (reg >> 2) + 4 * hi;
        int x = w * 32 + l31;
        kb[(size_t)p * 16384 + y * 128 + x] = f2h(acc[mo][r][reg] + bk[h * 64 + p]);
      }
    }
}

// ---------------- scores partials: 1024 blocks (4/CU), gload_lds staging ------
__global__ __launch_bounds__(256) void scoresk(const unsigned short* __restrict__ qin,
                                               const unsigned short* __restrict__ kin,
                                               float* __restrict__ part) {
  __shared__ __align__(16) unsigned short As[64 * 64];
  __shared__ __align__(16) unsigned short Bs[64 * 64];
  int nch = blockIdx.x, b = blockIdx.y, h = blockIdx.z;
  int tid = threadIdx.x, lane = tid & 63, w = tid >> 6;
  int l15 = lane & 15, uq = lane >> 4;
  const unsigned short* qb = qin + (size_t)((h * 8 + b) * 64) * 16384;
  const unsigned short* kb = kin + (size_t)((h * 8 + b) * 64) * 16384;
  int moff = (w >> 1) * 32, noff = (w & 1) * 32;
  const f32x4 fz = {0.f, 0.f, 0.f, 0.f};
  f32x4 acc[2][2] = {{fz, fz}, {fz, fz}};
  const unsigned short* srcb = (w < 2) ? qb : kb;
  unsigned short* dst = (w < 2) ? As : Bs;
  int pbase = (w & 1) * 64;  // wave-uniform
  for (int ci = 0; ci < 8; ci++) {
    int nb = nch * 512 + ci * 64;
    __syncthreads();
#pragma unroll
    for (int k4 = 0; k4 < 4; k4++) {
      int p = pbase + k4 * 128 + lane;
      int row = p >> 3, j = p & 7;
      int gs = j ^ (row & 7);
      const unsigned short* gsrc = srcb + (size_t)row * 16384 + nb + gs * 8;
      __builtin_amdgcn_global_load_lds(
          (const __attribute__((address_space(1))) void*)gsrc,
          (__attribute__((address_space(3))) void*)&dst[(size_t)(pbase + k4 * 128) * 8],
          16, 0, 0);
    }
    asm volatile("s_waitcnt vmcnt(0)" ::: "memory");
    __syncthreads();
#pragma unroll
    for (int kk = 0; kk < 2; kk++) {
      f16x8 b0 = *(const f16x8*)&Bs[sw(noff + l15, kk * 32 + uq * 8)];
      f16x8 b1 = *(const f16x8*)&Bs[sw(noff + 16 + l15, kk * 32 + uq * 8)];
      f16x8 a0 = *(const f16x8*)&As[sw(moff + l15, kk * 32 + uq * 8)];
      f16x8 a1 = *(const f16x8*)&As[sw(moff + 16 + l15, kk * 32 + uq * 8)];
      acc[0][0] = mfma16(a0, b0, acc[0][0]);
      acc[0][1] = mfma16(a0, b1, acc[0][1]);
      acc[1][0] = mfma16(a1, b0, acc[1][0]);
      acc[1][1] = mfma16(a1, b1, acc[1][1]);
    }
  }
  float* pb = part + (size_t)((nch * 4 + h) * 8 + b) * 4096;
#pragma unroll
  for (int mf = 0; mf < 2; mf++)
#pragma unroll
    for (int nf = 0; nf < 2; nf++) {
      int p = noff + nf * 16 + l15;
#pragma unroll
      for (int r = 0; r < 4; r++) {
        int o = moff + mf * 16 + 4 * uq + r;
        pb[o * 64 + p] = acc[mf][nf][r];
      }
    }
}

// ---------------- softmax over p (one wave per (h,b,o) row) ----------------
__global__ __launch_bounds__(256) void smax(const float* __restrict__ part,
                                            unsigned short* __restrict__ attn) {
  int row = blockIdx.x * 4 + (threadIdx.x >> 6);
  int lane = threadIdx.x & 63;
  int h = row >> 9, b = (row >> 6) & 7, o = row & 63;
  float s = 0.f;
#pragma unroll
  for (int nch = 0; nch < 32; nch++)
    s += part[(size_t)((nch * 4 + h) * 8 + b) * 4096 + o * 64 + lane];
  s *= 0.0625f;  // 1/sqrt(256)
  float m = s;
#pragma unroll
  for (int k = 32; k > 0; k >>= 1) m = fmaxf(m, __shfl_xor(m, k, 64));
  float e = __expf(s - m);
  float sum = e;
#pragma unroll
  for (int k = 32; k > 0; k >>= 1) sum += __shfl_xor(sum, k, 64);
  attn[(size_t)(h * 8 + b) * 4096 + o * 64 + lane] = f2h(e / sum);
}

// ---------------- out = attn @ v (staging via global_load_lds) ----------------
__global__ __launch_bounds__(256) void outk(const unsigned short* __restrict__ attn,
                                            const unsigned short* __restrict__ vT,
                                            float* __restrict__ out) {
  __shared__ __align__(16) unsigned short As[64 * 64];
  __shared__ __align__(16) unsigned short Bs[256 * 64];
  int n0 = blockIdx.x * 256, b = blockIdx.y, h = blockIdx.z;
  int tid = threadIdx.x, lane = tid & 63, w = tid >> 6;
  int l15 = lane & 15, uq = lane >> 4;
  const unsigned short* ab = attn + (size_t)(h * 8 + b) * 4096;
  const unsigned short* vb = vT + (size_t)(h * 8 + b) * 16384 * 64;
#pragma unroll
  for (int it = 0; it < 2; it++) {
    int base = it * 256 + w * 64;
    int p = base + lane;
    int row = p >> 3, j = p & 7;
    int gs = j ^ (row & 7);
    const unsigned short* gsrc = ab + row * 64 + gs * 8;
    __builtin_amdgcn_global_load_lds(
        (const __attribute__((address_space(1))) void*)gsrc,
        (__attribute__((address_space(3))) void*)&As[(size_t)base * 8], 16, 0, 0);
  }
#pragma unroll
  for (int it = 0; it < 8; it++) {
    int base = it * 256 + w * 64;
    int p = base + lane;
    int px = p >> 3, j = p & 7;
    int gs = j ^ (px & 7);
    const unsigned short* gsrc = vb + (size_t)(n0 + px) * 64 + gs * 8;
    __builtin_amdgcn_global_load_lds(
        (const __attribute__((address_space(1))) void*)gsrc,
        (__attribute__((address_space(3))) void*)&Bs[(size_t)base * 8], 16, 0, 0);
  }
  __syncthreads();
  const f32x4 fz = {0.f, 0.f, 0.f, 0.f};
  f32x4 acc[4][4];
#pragma unroll
  for (int i = 0; i < 4; i++)
#pragma unroll
    for (int j = 0; j < 4; j++) acc[i][j] = fz;
#pragma unroll
  for (int kk = 0; kk < 2; kk++) {
    f16x8 bfr[4];
#pragma unroll
    for (int nf = 0; nf < 4; nf++)
      bfr[nf] = *(const f16x8*)&Bs[sw(w * 64 + nf * 16 + l15, kk * 32 + uq * 8)];
#pragma unroll
    for (int mf = 0; mf < 4; mf++) {
      f16x8 afr = *(const f16x8*)&As[sw(mf * 16 + l15, kk * 32 + uq * 8)];
#pragma unroll
      for (int nf = 0; nf < 4; nf++) acc[mf][nf] = mfma16(afr, bfr[nf], acc[mf][nf]);
    }
  }
  float* ob = out + (size_t)b * 4194304 + (size_t)(h * 64) * 16384;
#pragma unroll
  for (int mf = 0; mf < 4; mf++)
#pragma unroll
    for (int nf = 0; nf < 4; nf++) {
      int n = n0 + w * 64 + nf * 16 + l15;
#pragma unroll
      for (int r = 0; r < 4; r++) {
        int o = mf * 16 + 4 * uq + r;
        ob[(size_t)o * 16384 + n] = acc[mf][nf][r];
      }
    }
}

extern "C" void kernel_launch(void* const* d_in, const int* in_sizes, int n_in,
                              void* d_out, int out_size, void* d_ws, size_t ws_size,
                              hipStream_t stream) {
  const float* x  = (const float*)d_in[0];
  const float* Wq = (const float*)d_in[1];
  const float* bq = (const float*)d_in[2];
  const float* Wk = (const float*)d_in[3];
  const float* bk = (const float*)d_in[4];
  const float* Wv = (const float*)d_in[5];
  const float* bv = (const float*)d_in[6];
  float* out = (float*)d_out;

  char* ws = (char*)d_ws;
  unsigned short* kbuf = (unsigned short*)(ws);
  unsigned short* vT   = (unsigned short*)(ws + 67108864);
  unsigned short* attn = (unsigned short*)(ws + 134217728);
  unsigned short* Wqvn = (unsigned short*)(ws + 134479872);
  unsigned short* Wkb  = (unsigned short*)(ws + 134742016);
  unsigned short* zp   = (unsigned short*)(ws + 135921664);
  // d_out doubles as scratch: xT2 in first half, q in second; part reuses dead xT2.
  unsigned short* xT = (unsigned short*)d_out;
  unsigned short* qb = (unsigned short*)d_out + 33554432;
  float* part = (float*)d_out;

  prep<<<dim3(2816), dim3(256), 0, stream>>>(Wq, Wv, Wk, Wqvn, Wkb, zp);
  xpose<<<dim3(256, 4, 8), dim3(256), 0, stream>>>(x, xT);
  proj<<<dim3(256, 8), dim3(256), 0, stream>>>(xT, Wqvn, bq, bv, qb, vT);
  convk<<<dim3(1024), dim3(256), 0, stream>>>(xT, Wkb, bk, zp, kbuf);
  scoresk<<<dim3(32, 8, 4), dim3(256), 0, stream>>>(qb, kbuf, part);
  smax<<<dim3(512), dim3(256), 0, stream>>>(part, attn);
  outk<<<dim3(64, 8, 4), dim3(256), 0, stream>>>(attn, vT, out);
}